// Round 10
// baseline (165.688 us; speedup 1.0000x reference)
//
#include <hip/hip_runtime.h>
#include <hip/hip_fp16.h>

#ifndef M_PIf
#define M_PIf 3.14159265358979323846f
#endif

constexpr int NNODE = 4000;
constexpr int NEDGE = 48000;
constexpr int NLA   = 20;
constexpr int NCH   = 9;
constexpr int NRB   = 8;
constexpr int NEL   = NRB * NLA * NCH;    // 1440
constexpr int NP2   = NEL / 2;            // 720 half2 pairs
constexpr int FW    = 40;                 // facS row width (floats)
constexpr int EC    = 32;                 // edge chunk per LDS stage
constexpr float CUT = 5.5f;
constexpr float MPN = 0.316227766016837933f;

__constant__ int   c_LOF[NLA]  = {0,1,1,1,2,2,2,2,2,2,3,3,3,3,3,3,3,3,3,3};
__constant__ float c_PREF[NLA] = {1,1,1,1,1,2,2,1,2,1,1,3,3,3,6,3,1,3,3,1};
__constant__ int   c_GB[4] = {0,0,1,4};
__constant__ int   c_GE[4] = {0,1,4,10};

__global__ void k_count(const int* __restrict__ ei, int* __restrict__ counts) {
  int e = blockIdx.x * blockDim.x + threadIdx.x;
  if (e >= NEDGE) return;
  atomicAdd(&counts[ei[NEDGE + e]], 1);
}

__global__ void k_scan(const int* __restrict__ counts, int* __restrict__ offsets,
                       int* __restrict__ cursor) {
  __shared__ int wsum[16];
  int t = threadIdx.x;
  int base = t*4;
  int c0 = (base+0 < NNODE) ? counts[base+0] : 0;
  int c1 = (base+1 < NNODE) ? counts[base+1] : 0;
  int c2 = (base+2 < NNODE) ? counts[base+2] : 0;
  int c3 = (base+3 < NNODE) ? counts[base+3] : 0;
  int s = c0+c1+c2+c3;
  int lane = t & 63, w = t >> 6;
  int incl = s;
  #pragma unroll
  for (int d = 1; d < 64; d <<= 1) {
    int v = __shfl_up(incl, d);
    if (lane >= d) incl += v;
  }
  if (lane == 63) wsum[w] = incl;
  __syncthreads();
  if (t < 16) {
    int v = wsum[t];
    int inc2 = v;
    #pragma unroll
    for (int d = 1; d < 16; d <<= 1) {
      int u = __shfl_up(inc2, d);
      if (t >= d) inc2 += u;
    }
    wsum[t] = inc2 - v;   // exclusive wave prefix
  }
  __syncthreads();
  int excl = wsum[w] + incl - s;
  int o0 = excl, o1 = o0+c0, o2 = o1+c1, o3 = o2+c2;
  if (base+0 < NNODE) { offsets[base+0]=o0; cursor[base+0]=o0; }
  if (base+1 < NNODE) { offsets[base+1]=o1; cursor[base+1]=o1; }
  if (base+2 < NNODE) { offsets[base+2]=o2; cursor[base+2]=o2; }
  if (base+3 < NNODE) { offsets[base+3]=o3; cursor[base+3]=o3; }
  if (t == 1023) offsets[NNODE] = excl + s;
}

__global__ void k_edgec(const float* __restrict__ pos, const float* __restrict__ shifts,
                        const int* __restrict__ ei, const int* __restrict__ an,
                        const float* __restrict__ W_emb,
                        int* __restrict__ cursor, float* __restrict__ facS,
                        int* __restrict__ sndS) {
  int e = blockIdx.x * blockDim.x + threadIdx.x;
  if (e >= NEDGE) return;
  int snd = ei[e];
  int rcv = ei[NEDGE + e];
  float vx = pos[rcv*3+0] - pos[snd*3+0] + shifts[e*3+0];
  float vy = pos[rcv*3+1] - pos[snd*3+1] + shifts[e*3+1];
  float vz = pos[rcv*3+2] - pos[snd*3+2] + shifts[e*3+2];
  float len = sqrtf(vx*vx + vy*vy + vz*vz);
  float inv = 1.0f / len;
  float x = vx*inv, y = vy*inv, z = vz*inv;
  float u  = len * (1.0f/CUT);
  float u2 = u*u;
  float u6 = u2*u2*u2;
  float fcut = 1.0f - 28.0f*u6 + 48.0f*u6*u - 21.0f*u6*u2;
  if (u >= 1.0f) fcut = 0.0f;
  float pre = sqrtf(2.0f/CUT) * fcut * inv;
  int p = atomicAdd(&cursor[rcv], 1);
  float* f = facS + (size_t)p*FW;
  // sin(n*pi*u) via Chebyshev recurrence
  float s1, cth;
  __sincosf(M_PIf * u, &s1, &cth);
  float two_c = 2.0f * cth;
  float sm1 = 0.0f, sc = s1;
  #pragma unroll
  for (int j = 0; j < NRB; ++j) {
    f[j] = pre * sc;
    float nx = two_c * sc - sm1;
    sm1 = sc; sc = nx;
  }
  float ang[NLA];
  ang[0]=1.0f; ang[1]=x; ang[2]=y; ang[3]=z;
  ang[4]=x*x; ang[5]=x*y; ang[6]=x*z; ang[7]=y*y; ang[8]=y*z; ang[9]=z*z;
  ang[10]=ang[4]*x; ang[11]=ang[4]*y; ang[12]=ang[4]*z;
  ang[13]=x*ang[7]; ang[14]=ang[5]*z; ang[15]=x*ang[9];
  ang[16]=ang[7]*y; ang[17]=ang[7]*z; ang[18]=y*ang[9]; ang[19]=ang[9]*z;
  #pragma unroll
  for (int i = 0; i < NLA; ++i) f[8+i] = ang[i];
  int as_ = an[snd], ar_ = an[rcv];
  int sps = (as_==1)?0:(as_==6)?1:(as_==7)?2:3;
  int spr = (ar_==1)?0:(ar_==6)?1:(ar_==7)?2:3;
  float es0=W_emb[sps*3+0], es1=W_emb[sps*3+1], es2=W_emb[sps*3+2];
  float er0=W_emb[spr*3+0], er1=W_emb[spr*3+1], er2=W_emb[spr*3+2];
  f[28]=es0*er0; f[29]=es0*er1; f[30]=es0*er2;
  f[31]=es1*er0; f[32]=es1*er1; f[33]=es1*er2;
  f[34]=es2*er0; f[35]=es2*er1; f[36]=es2*er2;
  f[37]=0.f; f[38]=0.f; f[39]=0.f;
  sndS[p] = snd;
}

__global__ void k_echi(const float* __restrict__ facS, const int* __restrict__ sndS,
                       const float* __restrict__ chi, float* __restrict__ echiS) {
  int p = blockIdx.x * blockDim.x + threadIdx.x;
  if (p >= NEDGE) return;
  int snd = sndS[p];
  const float* f = facS + (size_t)p*FW;
  float* o = echiS + (size_t)p*12;
  #pragma unroll
  for (int c = 0; c < 9; ++c)
    o[c] = chi[snd*9 + c] * f[28 + c];
  o[9] = 0.f; o[10] = 0.f; o[11] = 0.f;
}

// ---- split-node kernels: block = (node,half); 360 half2-pairs per block.
// Balanced ownership: q0 = t; q1 = 256 + wave*26 + lane (lane<26) -> 90 pairs/wave.

__global__ __launch_bounds__(256, 8) void k_nodeA(
    const float* __restrict__ facS, const int* __restrict__ offsets,
    const float* __restrict__ W_rt,
    __half2* __restrict__ A1h2,
    float* __restrict__ chi, float* __restrict__ out) {
  __shared__ float s_wrt[256];
  __shared__ float s_e[EC*FW];
  __shared__ float s_tile[8*90];
  __shared__ float s_B[288];
  int bid = blockIdx.x;
  int n = bid >> 1, half = bid & 1;
  int t = threadIdx.x;
  s_wrt[t] = W_rt[t];
  int lane = t & 63, w = t >> 6;
  bool act1 = (lane < 26);
  int q[2];
  q[0] = t;
  q[1] = act1 ? (256 + w*26 + lane) : 0;
  int rq[2], kk[2], qg[2], i0[2], c0[2], l0[2], i1[2], c1[2], l1[2];
  #pragma unroll
  for (int jj = 0; jj < 2; ++jj) {
    rq[jj] = q[jj] / 45; kk[jj] = q[jj] % 45;
    qg[jj] = rq[jj]*90 + kk[jj] + half*45;
    int rem0 = 2*(kk[jj] + 45*half);
    i0[jj] = rem0 / 9;  c0[jj] = rem0 % 9;  l0[jj] = c_LOF[i0[jj]];
    int rem1 = rem0 + 1;
    i1[jj] = rem1 / 9;  c1[jj] = rem1 % 9;  l1[jj] = c_LOF[i1[jj]];
  }
  float acc[2][2] = {{0,0},{0,0}};
  int beg = offsets[n], end = offsets[n+1];
  const float4* f4 = (const float4*)facS;
  for (int base = beg; base < end; base += EC) {
    int m = min(EC, end - base);
    __syncthreads();
    for (int idx = t; idx < m*(FW/4); idx += 256)
      ((float4*)s_e)[idx] = f4[(size_t)base*(FW/4) + idx];
    __syncthreads();
    for (int p = 0; p < m; ++p) {
      const float* e0 = s_e + p*FW;
      {
        float rv = e0[rq[0]];
        acc[0][0] += rv * e0[8+i0[0]] * e0[28+c0[0]];
        acc[0][1] += rv * e0[8+i1[0]] * e0[28+c1[0]];
      }
      if (act1) {
        float rv = e0[rq[1]];
        acc[1][0] += rv * e0[8+i0[1]] * e0[28+c1[1]-c1[1]+c0[1]];
        acc[1][1] += rv * e0[8+i1[1]] * e0[28+c1[1]];
      }
    }
  }
  __syncthreads();
  s_tile[rq[0]*90 + 2*kk[0]]     = acc[0][0];
  s_tile[rq[0]*90 + 2*kk[0] + 1] = acc[0][1];
  if (act1) {
    s_tile[rq[1]*90 + 2*kk[1]]     = acc[1][0];
    s_tile[rq[1]*90 + 2*kk[1] + 1] = acc[1][1];
  }
  __syncthreads();
  float a1v[2][2];
  #pragma unroll
  for (int jj = 0; jj < 2; ++jj) {
    if (jj == 0 || act1) {
      float ab0 = 0.f, ab1 = 0.f;
      #pragma unroll
      for (int r = 0; r < NRB; ++r) {
        ab0 += s_tile[r*90 + 2*kk[jj]]     * s_wrt[l0[jj]*64 + r*8 + rq[jj]];
        ab1 += s_tile[r*90 + 2*kk[jj] + 1] * s_wrt[l1[jj]*64 + r*8 + rq[jj]];
      }
      a1v[jj][0] = ab0; a1v[jj][1] = ab1;
      A1h2[(size_t)n*NP2 + qg[jj]] = __floats2half2_rn(ab0, ab1);
    }
  }
  __syncthreads();
  s_tile[rq[0]*90 + 2*kk[0]]     = a1v[0][0];
  s_tile[rq[0]*90 + 2*kk[0] + 1] = a1v[0][1];
  if (act1) {
    s_tile[rq[1]*90 + 2*kk[1]]     = a1v[1][0];
    s_tile[rq[1]*90 + 2*kk[1] + 1] = a1v[1][1];
  }
  __syncthreads();
  if (half == 0) {
    for (int m2 = t; m2 < 288; m2 += 256) {
      int s = m2 / 36, rm = m2 % 36, l5 = rm / 9, c = rm % 9;
      float b;
      if (l5 == 0) b = s_tile[s*90 + c];
      else {
        b = 0.f;
        for (int i = c_GB[l5]; i < c_GE[l5]; ++i) {
          float v = s_tile[s*90 + i*9 + c];
          b += c_PREF[i]*v*v;
        }
      }
      out[(size_t)(((n*8 + s)*5 + l5)*9 + c)*2 + 0] = b;
      s_B[m2] = b;
    }
    __syncthreads();
    if (t < 9) {
      float x = 0.f;
      #pragma unroll
      for (int u = 0; u < 32; ++u) x += s_B[u*9 + t];
      atomicAdd(&chi[n*9 + t], x);
    }
  } else {
    if (t < 72) {
      int s = t / 9, c = t % 9;
      float b = 0.f;
      for (int i = 10; i < 20; ++i) {
        float v = s_tile[s*90 + (i-10)*9 + c];
        b += c_PREF[i]*v*v;
      }
      out[(size_t)(((n*8 + s)*5 + 4)*9 + c)*2 + 0] = b;
      s_B[t] = b;
    }
    __syncthreads();
    if (t < 9) {
      float x = 0.f;
      #pragma unroll
      for (int u = 0; u < 8; ++u) x += s_B[u*9 + t];
      atomicAdd(&chi[n*9 + t], x);
    }
  }
}

__global__ __launch_bounds__(256, 8) void k_nodeMP(
    const float* __restrict__ facS, const int* __restrict__ offsets,
    const int* __restrict__ sndS, const float* __restrict__ echiS,
    const float* __restrict__ W_rt, const float* __restrict__ W_nm,
    const __half2* __restrict__ A1h2,
    float* __restrict__ out) {
  __shared__ float s_wrt[256];
  __shared__ float s_wnm[288];
  __shared__ float s_e[EC*28];
  __shared__ float s_ec[EC*12];
  __shared__ float s_tile[8*90];
  int bid = blockIdx.x;
  int n = bid >> 1, half = bid & 1;
  int t = threadIdx.x;
  s_wrt[t] = W_rt[t];
  s_wnm[t] = W_nm[t];
  if (t < 32) s_wnm[256 + t] = W_nm[256 + t];
  int lane = t & 63, w = t >> 6;
  bool act1 = (lane < 26);
  int q[2];
  q[0] = t;
  q[1] = act1 ? (256 + w*26 + lane) : 0;
  int rq[2], kk[2], qg[2], i0[2], c0[2], l0[2], i1[2], c1[2], l1[2];
  #pragma unroll
  for (int jj = 0; jj < 2; ++jj) {
    rq[jj] = q[jj] / 45; kk[jj] = q[jj] % 45;
    qg[jj] = rq[jj]*90 + kk[jj] + half*45;
    int rem0 = 2*(kk[jj] + 45*half);
    i0[jj] = rem0 / 9;  c0[jj] = rem0 % 9;  l0[jj] = c_LOF[i0[jj]];
    int rem1 = rem0 + 1;
    i1[jj] = rem1 / 9;  c1[jj] = rem1 % 9;  l1[jj] = c_LOF[i1[jj]];
  }
  float accA[2][2] = {{0,0},{0,0}};
  float accB[2][2] = {{0,0},{0,0}};
  float2 mymem[2];
  mymem[0] = __half22float2(A1h2[(size_t)n*NP2 + qg[0]]);
  mymem[1] = act1 ? __half22float2(A1h2[(size_t)n*NP2 + qg[1]]) : make_float2(0.f,0.f);
  int beg = offsets[n], end = offsets[n+1];
  const float4* f4 = (const float4*)facS;
  const float4* e4 = (const float4*)echiS;
  for (int base = beg; base < end; base += EC) {
    int m = min(EC, end - base);
    __syncthreads();
    for (int idx = t; idx < m*7; idx += 256) {
      int p = idx / 7, qd = idx - p*7;
      ((float4*)(s_e + p*28))[qd] = f4[(size_t)(base+p)*10 + qd];
    }
    for (int idx = t; idx < m*3; idx += 256)
      ((float4*)s_ec)[idx] = e4[(size_t)base*3 + idx];
    __syncthreads();
    int p = 0;
    for (; p + 3 < m; p += 4) {
      int sd0 = sndS[base+p+0], sd1 = sndS[base+p+1];
      int sd2 = sndS[base+p+2], sd3 = sndS[base+p+3];
      __half2 g0a = A1h2[(size_t)sd0*NP2 + qg[0]];
      __half2 g1a = A1h2[(size_t)sd1*NP2 + qg[0]];
      __half2 g2a = A1h2[(size_t)sd2*NP2 + qg[0]];
      __half2 g3a = A1h2[(size_t)sd3*NP2 + qg[0]];
      __half2 g0b, g1b, g2b, g3b;
      if (act1) {
        g0b = A1h2[(size_t)sd0*NP2 + qg[1]];
        g1b = A1h2[(size_t)sd1*NP2 + qg[1]];
        g2b = A1h2[(size_t)sd2*NP2 + qg[1]];
        g3b = A1h2[(size_t)sd3*NP2 + qg[1]];
      }
      #pragma unroll
      for (int x = 0; x < 4; ++x) {
        const float* e0 = s_e + (p+x)*28;
        const float* x0 = s_ec + (p+x)*12;
        __half2 ga = (x==0)?g0a:(x==1)?g1a:(x==2)?g2a:g3a;
        {
          float rv = e0[rq[0]];
          float2 gf = __half22float2(ga);
          accA[0][0] += gf.x * rv;
          accA[0][1] += gf.y * rv;
          accB[0][0] += rv * e0[8+i0[0]] * x0[c0[0]];
          accB[0][1] += rv * e0[8+i1[0]] * x0[c1[0]];
        }
        if (act1) {
          __half2 gb = (x==0)?g0b:(x==1)?g1b:(x==2)?g2b:g3b;
          float rv = e0[rq[1]];
          float2 gf = __half22float2(gb);
          accA[1][0] += gf.x * rv;
          accA[1][1] += gf.y * rv;
          accB[1][0] += rv * e0[8+i0[1]] * x0[c0[1]];
          accB[1][1] += rv * e0[8+i1[1]] * x0[c1[1]];
        }
      }
    }
    for (; p < m; ++p) {
      int sd = sndS[base+p];
      const float* e0 = s_e + p*28;
      const float* x0 = s_ec + p*12;
      const __half2* Ah = A1h2 + (size_t)sd*NP2;
      {
        float rv = e0[rq[0]];
        float2 gf = __half22float2(Ah[qg[0]]);
        accA[0][0] += gf.x * rv;
        accA[0][1] += gf.y * rv;
        accB[0][0] += rv * e0[8+i0[0]] * x0[c0[0]];
        accB[0][1] += rv * e0[8+i1[0]] * x0[c1[0]];
      }
      if (act1) {
        float rv = e0[rq[1]];
        float2 gf = __half22float2(Ah[qg[1]]);
        accA[1][0] += gf.x * rv;
        accA[1][1] += gf.y * rv;
        accB[1][0] += rv * e0[8+i0[1]] * x0[c0[1]];
        accB[1][1] += rv * e0[8+i1[1]] * x0[c1[1]];
      }
    }
  }
  __syncthreads();
  s_tile[rq[0]*90 + 2*kk[0]]     = accB[0][0];
  s_tile[rq[0]*90 + 2*kk[0] + 1] = accB[0][1];
  if (act1) {
    s_tile[rq[1]*90 + 2*kk[1]]     = accB[1][0];
    s_tile[rq[1]*90 + 2*kk[1] + 1] = accB[1][1];
  }
  __syncthreads();
  float a2v[2][2];
  #pragma unroll
  for (int jj = 0; jj < 2; ++jj) {
    if (jj == 0 || act1) {
      float ab0 = 0.f, ab1 = 0.f;
      #pragma unroll
      for (int r = 0; r < NRB; ++r) {
        ab0 += s_tile[r*90 + 2*kk[jj]]     * s_wrt[l0[jj]*64 + r*8 + rq[jj]];
        ab1 += s_tile[r*90 + 2*kk[jj] + 1] * s_wrt[l1[jj]*64 + r*8 + rq[jj]];
      }
      float mem0 = mymem[jj].x * s_wnm[rq[jj]*36 + l0[jj]*9 + c0[jj]];
      float mem1 = mymem[jj].y * s_wnm[rq[jj]*36 + l1[jj]*9 + c1[jj]];
      a2v[jj][0] = (ab0 + accA[jj][0])*MPN + mem0;
      a2v[jj][1] = (ab1 + accA[jj][1])*MPN + mem1;
    }
  }
  __syncthreads();
  s_tile[rq[0]*90 + 2*kk[0]]     = a2v[0][0];
  s_tile[rq[0]*90 + 2*kk[0] + 1] = a2v[0][1];
  if (act1) {
    s_tile[rq[1]*90 + 2*kk[1]]     = a2v[1][0];
    s_tile[rq[1]*90 + 2*kk[1] + 1] = a2v[1][1];
  }
  __syncthreads();
  if (half == 0) {
    for (int m2 = t; m2 < 288; m2 += 256) {
      int s = m2 / 36, rm = m2 % 36, l5 = rm / 9, c = rm % 9;
      float b;
      if (l5 == 0) b = s_tile[s*90 + c];
      else {
        b = 0.f;
        for (int i = c_GB[l5]; i < c_GE[l5]; ++i) {
          float v = s_tile[s*90 + i*9 + c];
          b += c_PREF[i]*v*v;
        }
      }
      out[(size_t)(((n*8 + s)*5 + l5)*9 + c)*2 + 1] = b;
    }
  } else {
    if (t < 72) {
      int s = t / 9, c = t % 9;
      float b = 0.f;
      for (int i = 10; i < 20; ++i) {
        float v = s_tile[s*90 + (i-10)*9 + c];
        b += c_PREF[i]*v*v;
      }
      out[(size_t)(((n*8 + s)*5 + 4)*9 + c)*2 + 1] = b;
    }
  }
}

extern "C" void kernel_launch(void* const* d_in, const int* in_sizes, int n_in,
                              void* d_out, int out_size, void* d_ws, size_t ws_size,
                              hipStream_t stream) {
  const float* pos    = (const float*)d_in[0];
  const float* shifts = (const float*)d_in[1];
  const float* W_emb  = (const float*)d_in[2];
  const float* W_rt   = (const float*)d_in[3];
  const float* W_nm   = (const float*)d_in[4];
  const int*   an     = (const int*)d_in[5];
  const int*   ei     = (const int*)d_in[6];
  float* out = (float*)d_out;

  char* ws = (char*)d_ws;
  size_t off = 0;
  auto carve = [&](size_t bytes) {
    void* p = ws + off;
    off = (off + bytes + 255) & ~(size_t)255;
    return p;
  };
  float*   facS    = (float*)carve((size_t)FW*NEDGE*sizeof(float));
  int*     sndS    = (int*)carve((size_t)NEDGE*sizeof(int));
  float*   echiS   = (float*)carve((size_t)12*NEDGE*sizeof(float));
  __half2* A1h2    = (__half2*)carve((size_t)NNODE*NEL*sizeof(__half));
  float*   chi     = (float*)carve((size_t)NNODE*NCH*sizeof(float));
  int*     counts  = (int*)carve((size_t)NNODE*sizeof(int));
  int*     offsets = (int*)carve((size_t)(NNODE+1)*sizeof(int));
  int*     cursor  = (int*)carve((size_t)NNODE*sizeof(int));

  size_t z0 = (size_t)((char*)chi - ws);
  size_t z1 = (size_t)((char*)counts - ws) + (size_t)NNODE*sizeof(int);
  hipMemsetAsync((char*)ws + z0, 0, z1 - z0, stream);
  k_count<<<(NEDGE+255)/256, 256, 0, stream>>>(ei, counts);
  k_scan<<<1, 1024, 0, stream>>>(counts, offsets, cursor);
  k_edgec<<<(NEDGE+255)/256, 256, 0, stream>>>(pos, shifts, ei, an, W_emb, cursor, facS, sndS);
  k_nodeA<<<NNODE*2, 256, 0, stream>>>(facS, offsets, W_rt, A1h2, chi, out);
  k_echi<<<(NEDGE+255)/256, 256, 0, stream>>>(facS, sndS, chi, echiS);
  k_nodeMP<<<NNODE*2, 256, 0, stream>>>(facS, offsets, sndS, echiS, W_rt, W_nm, A1h2, out);
}

// Round 11
// 119.563 us; speedup vs baseline: 1.3858x; 1.3858x over previous
//
#include <hip/hip_runtime.h>
#include <hip/hip_fp16.h>

#ifndef M_PIf
#define M_PIf 3.14159265358979323846f
#endif

constexpr int NNODE = 4000;
constexpr int NEDGE = 48000;
constexpr int NLA   = 20;
constexpr int NCH   = 9;
constexpr int NRB   = 8;
constexpr int NEL   = NRB * NLA * NCH;    // 1440
constexpr int NP2   = NEL / 2;            // 720 half2 pairs
constexpr int FW    = 40;                 // facS row width (floats)
constexpr int EC    = 32;                 // edge chunk per LDS stage
constexpr float CUT = 5.5f;
constexpr float MPN = 0.316227766016837933f;

__constant__ int   c_LOF[NLA]  = {0,1,1,1,2,2,2,2,2,2,3,3,3,3,3,3,3,3,3,3};
__constant__ float c_PREF[NLA] = {1,1,1,1,1,2,2,1,2,1,1,3,3,3,6,3,1,3,3,1};
__constant__ int   c_GB[4] = {0,0,1,4};
__constant__ int   c_GE[4] = {0,1,4,10};

__global__ void k_count(const int* __restrict__ ei, int* __restrict__ counts) {
  int e = blockIdx.x * blockDim.x + threadIdx.x;
  if (e >= NEDGE) return;
  atomicAdd(&counts[ei[NEDGE + e]], 1);
}

__global__ void k_scan(const int* __restrict__ counts, int* __restrict__ offsets,
                       int* __restrict__ cursor) {
  __shared__ int wsum[16];
  int t = threadIdx.x;
  int base = t*4;
  int c0 = (base+0 < NNODE) ? counts[base+0] : 0;
  int c1 = (base+1 < NNODE) ? counts[base+1] : 0;
  int c2 = (base+2 < NNODE) ? counts[base+2] : 0;
  int c3 = (base+3 < NNODE) ? counts[base+3] : 0;
  int s = c0+c1+c2+c3;
  int lane = t & 63, w = t >> 6;
  int incl = s;
  #pragma unroll
  for (int d = 1; d < 64; d <<= 1) {
    int v = __shfl_up(incl, d);
    if (lane >= d) incl += v;
  }
  if (lane == 63) wsum[w] = incl;
  __syncthreads();
  if (t < 16) {
    int v = wsum[t];
    int inc2 = v;
    #pragma unroll
    for (int d = 1; d < 16; d <<= 1) {
      int u = __shfl_up(inc2, d);
      if (t >= d) inc2 += u;
    }
    wsum[t] = inc2 - v;   // exclusive wave prefix
  }
  __syncthreads();
  int excl = wsum[w] + incl - s;
  int o0 = excl, o1 = o0+c0, o2 = o1+c1, o3 = o2+c2;
  if (base+0 < NNODE) { offsets[base+0]=o0; cursor[base+0]=o0; }
  if (base+1 < NNODE) { offsets[base+1]=o1; cursor[base+1]=o1; }
  if (base+2 < NNODE) { offsets[base+2]=o2; cursor[base+2]=o2; }
  if (base+3 < NNODE) { offsets[base+3]=o3; cursor[base+3]=o3; }
  if (t == 1023) offsets[NNODE] = excl + s;
}

__global__ void k_edgec(const float* __restrict__ pos, const float* __restrict__ shifts,
                        const int* __restrict__ ei, const int* __restrict__ an,
                        const float* __restrict__ W_emb,
                        int* __restrict__ cursor, float* __restrict__ facS,
                        int* __restrict__ sndS) {
  int e = blockIdx.x * blockDim.x + threadIdx.x;
  if (e >= NEDGE) return;
  int snd = ei[e];
  int rcv = ei[NEDGE + e];
  float vx = pos[rcv*3+0] - pos[snd*3+0] + shifts[e*3+0];
  float vy = pos[rcv*3+1] - pos[snd*3+1] + shifts[e*3+1];
  float vz = pos[rcv*3+2] - pos[snd*3+2] + shifts[e*3+2];
  float len = sqrtf(vx*vx + vy*vy + vz*vz);
  float inv = 1.0f / len;
  float x = vx*inv, y = vy*inv, z = vz*inv;
  float u  = len * (1.0f/CUT);
  float u2 = u*u;
  float u6 = u2*u2*u2;
  float fcut = 1.0f - 28.0f*u6 + 48.0f*u6*u - 21.0f*u6*u2;
  if (u >= 1.0f) fcut = 0.0f;
  float pre = sqrtf(2.0f/CUT) * fcut * inv;
  int p = atomicAdd(&cursor[rcv], 1);
  float* f = facS + (size_t)p*FW;
  // sin(n*pi*u) via Chebyshev recurrence: 1 sincos + FMAs
  float s1 = __sinf(M_PIf * u);
  float cth = __cosf(M_PIf * u);
  float two_c = 2.0f * cth;
  float sm1 = 0.0f, sc = s1;
  #pragma unroll
  for (int j = 0; j < NRB; ++j) {
    f[j] = pre * sc;
    float nx = two_c * sc - sm1;
    sm1 = sc; sc = nx;
  }
  float ang[NLA];
  ang[0]=1.0f; ang[1]=x; ang[2]=y; ang[3]=z;
  ang[4]=x*x; ang[5]=x*y; ang[6]=x*z; ang[7]=y*y; ang[8]=y*z; ang[9]=z*z;
  ang[10]=ang[4]*x; ang[11]=ang[4]*y; ang[12]=ang[4]*z;
  ang[13]=x*ang[7]; ang[14]=ang[5]*z; ang[15]=x*ang[9];
  ang[16]=ang[7]*y; ang[17]=ang[7]*z; ang[18]=y*ang[9]; ang[19]=ang[9]*z;
  #pragma unroll
  for (int i = 0; i < NLA; ++i) f[8+i] = ang[i];
  int as_ = an[snd], ar_ = an[rcv];
  int sps = (as_==1)?0:(as_==6)?1:(as_==7)?2:3;
  int spr = (ar_==1)?0:(ar_==6)?1:(ar_==7)?2:3;
  float es0=W_emb[sps*3+0], es1=W_emb[sps*3+1], es2=W_emb[sps*3+2];
  float er0=W_emb[spr*3+0], er1=W_emb[spr*3+1], er2=W_emb[spr*3+2];
  f[28]=es0*er0; f[29]=es0*er1; f[30]=es0*er2;
  f[31]=es1*er0; f[32]=es1*er1; f[33]=es1*er2;
  f[34]=es2*er0; f[35]=es2*er1; f[36]=es2*er2;
  f[37]=0.f; f[38]=0.f; f[39]=0.f;
  sndS[p] = snd;
}

__global__ void k_echi(const float* __restrict__ facS, const int* __restrict__ sndS,
                       const float* __restrict__ chi, float* __restrict__ echiS) {
  int p = blockIdx.x * blockDim.x + threadIdx.x;
  if (p >= NEDGE) return;
  int snd = sndS[p];
  const float* f = facS + (size_t)p*FW;
  float* o = echiS + (size_t)p*12;
  #pragma unroll
  for (int c = 0; c < 9; ++c)
    o[c] = chi[snd*9 + c] * f[28 + c];
  o[9] = 0.f; o[10] = 0.f; o[11] = 0.f;
}

// ---- split-node kernels (R9 mapping): block = (node,half);
// pair slot j in [0,360): r = j/45, kk = j%45; global half2-pair q = r*90+kk+45*half
// j0 = t (valid always), j1 = t+256 (valid t<104)

__global__ __launch_bounds__(256, 8) void k_nodeA(
    const float* __restrict__ facS, const int* __restrict__ offsets,
    const float* __restrict__ W_rt,
    float2* __restrict__ A1f2, __half2* __restrict__ A1h2,
    float* __restrict__ chi) {
  __shared__ float s_wrt[256];
  __shared__ float s_e[EC*FW];
  __shared__ float s_tile[8*90];
  __shared__ float s_B[288];
  int bid = blockIdx.x;
  int n = bid >> 1, half = bid & 1;
  int t = threadIdx.x;
  s_wrt[t] = W_rt[t];
  int rq[2], kk[2], i0[2], c0[2], l0[2], i1[2], c1[2], l1[2], qg[2];
  bool val[2];
  #pragma unroll
  for (int jj = 0; jj < 2; ++jj) {
    int j = t + jj*256;
    val[jj] = (j < 360);
    int js = val[jj] ? j : 0;
    rq[jj] = js / 45; kk[jj] = js % 45;
    qg[jj] = rq[jj]*90 + kk[jj] + half*45;
    int rem0 = 2*(kk[jj] + 45*half);
    i0[jj] = rem0 / 9;  c0[jj] = rem0 % 9;  l0[jj] = c_LOF[i0[jj]];
    int rem1 = rem0 + 1;
    i1[jj] = rem1 / 9;  c1[jj] = rem1 % 9;  l1[jj] = c_LOF[i1[jj]];
  }
  float acc[2][2] = {{0,0},{0,0}};
  int beg = offsets[n], end = offsets[n+1];
  const float4* f4 = (const float4*)facS;
  for (int base = beg; base < end; base += EC) {
    int m = min(EC, end - base);
    __syncthreads();
    for (int idx = t; idx < m*(FW/4); idx += 256)
      ((float4*)s_e)[idx] = f4[(size_t)base*(FW/4) + idx];
    __syncthreads();
    for (int p = 0; p < m; ++p) {
      const float* e0 = s_e + p*FW;
      #pragma unroll
      for (int jj = 0; jj < 2; ++jj) {
        if (val[jj]) {
          float rv = e0[rq[jj]];
          acc[jj][0] += rv * e0[8+i0[jj]] * e0[28+c0[jj]];
          acc[jj][1] += rv * e0[8+i1[jj]] * e0[28+c1[jj]];
        }
      }
    }
  }
  __syncthreads();
  #pragma unroll
  for (int jj = 0; jj < 2; ++jj)
    if (val[jj]) {
      s_tile[rq[jj]*90 + 2*kk[jj]]     = acc[jj][0];
      s_tile[rq[jj]*90 + 2*kk[jj] + 1] = acc[jj][1];
    }
  __syncthreads();
  float a1v[2][2];
  #pragma unroll
  for (int jj = 0; jj < 2; ++jj) {
    if (val[jj]) {
      float ab0 = 0.f, ab1 = 0.f;
      #pragma unroll
      for (int r = 0; r < NRB; ++r) {
        ab0 += s_tile[r*90 + 2*kk[jj]]     * s_wrt[l0[jj]*64 + r*8 + rq[jj]];
        ab1 += s_tile[r*90 + 2*kk[jj] + 1] * s_wrt[l1[jj]*64 + r*8 + rq[jj]];
      }
      a1v[jj][0] = ab0; a1v[jj][1] = ab1;
      size_t qi = (size_t)n*NP2 + qg[jj];
      A1f2[qi] = make_float2(ab0, ab1);
      A1h2[qi] = __floats2half2_rn(ab0, ab1);
    }
  }
  __syncthreads();
  #pragma unroll
  for (int jj = 0; jj < 2; ++jj)
    if (val[jj]) {
      s_tile[rq[jj]*90 + 2*kk[jj]]     = a1v[jj][0];
      s_tile[rq[jj]*90 + 2*kk[jj] + 1] = a1v[jj][1];
    }
  __syncthreads();
  // chi only (B/feats0 written later by k_nodeMP as float2)
  if (half == 0) {
    for (int m2 = t; m2 < 288; m2 += 256) {
      int s = m2 / 36, rm = m2 % 36, l5 = rm / 9, c = rm % 9;
      float b;
      if (l5 == 0) b = s_tile[s*90 + c];
      else {
        b = 0.f;
        for (int i = c_GB[l5]; i < c_GE[l5]; ++i) {
          float v = s_tile[s*90 + i*9 + c];
          b += c_PREF[i]*v*v;
        }
      }
      s_B[m2] = b;
    }
    __syncthreads();
    if (t < 9) {
      float x = 0.f;
      #pragma unroll
      for (int u = 0; u < 32; ++u) x += s_B[u*9 + t];
      atomicAdd(&chi[n*9 + t], x);
    }
  } else {
    if (t < 72) {
      int s = t / 9, c = t % 9;
      float b = 0.f;
      for (int i = 10; i < 20; ++i) {
        float v = s_tile[s*90 + (i-10)*9 + c];
        b += c_PREF[i]*v*v;
      }
      s_B[t] = b;
    }
    __syncthreads();
    if (t < 9) {
      float x = 0.f;
      #pragma unroll
      for (int u = 0; u < 8; ++u) x += s_B[u*9 + t];
      atomicAdd(&chi[n*9 + t], x);
    }
  }
}

__global__ __launch_bounds__(256, 8) void k_nodeMP(
    const float* __restrict__ facS, const int* __restrict__ offsets,
    const int* __restrict__ sndS, const float* __restrict__ echiS,
    const float* __restrict__ W_rt, const float* __restrict__ W_nm,
    const float2* __restrict__ A1f2, const __half2* __restrict__ A1h2,
    float* __restrict__ out) {
  __shared__ float s_wrt[256];
  __shared__ float s_wnm[288];
  __shared__ float s_e[EC*FW];     // reused as a1 tile (720 floats) in epilogue
  __shared__ float s_ec[EC*12];
  __shared__ float s_tile[8*90];
  int bid = blockIdx.x;
  int n = bid >> 1, half = bid & 1;
  int t = threadIdx.x;
  s_wrt[t] = W_rt[t];
  s_wnm[t] = W_nm[t];
  if (t < 32) s_wnm[256 + t] = W_nm[256 + t];
  int rq[2], kk[2], i0[2], c0[2], l0[2], i1[2], c1[2], l1[2], qg[2];
  bool val[2];
  #pragma unroll
  for (int jj = 0; jj < 2; ++jj) {
    int j = t + jj*256;
    val[jj] = (j < 360);
    int js = val[jj] ? j : 0;
    rq[jj] = js / 45; kk[jj] = js % 45;
    qg[jj] = rq[jj]*90 + kk[jj] + half*45;
    int rem0 = 2*(kk[jj] + 45*half);
    i0[jj] = rem0 / 9;  c0[jj] = rem0 % 9;  l0[jj] = c_LOF[i0[jj]];
    int rem1 = rem0 + 1;
    i1[jj] = rem1 / 9;  c1[jj] = rem1 % 9;  l1[jj] = c_LOF[i1[jj]];
  }
  float accA[2][2] = {{0,0},{0,0}};
  float accB[2][2] = {{0,0},{0,0}};
  float2 mymem[2];
  #pragma unroll
  for (int jj = 0; jj < 2; ++jj)
    mymem[jj] = val[jj] ? A1f2[(size_t)n*NP2 + qg[jj]] : make_float2(0.f, 0.f);
  int beg = offsets[n], end = offsets[n+1];
  const float4* f4 = (const float4*)facS;
  const float4* e4 = (const float4*)echiS;
  for (int base = beg; base < end; base += EC) {
    int m = min(EC, end - base);
    __syncthreads();
    for (int idx = t; idx < m*(FW/4); idx += 256)
      ((float4*)s_e)[idx] = f4[(size_t)base*(FW/4) + idx];
    for (int idx = t; idx < m*3; idx += 256)
      ((float4*)s_ec)[idx] = e4[(size_t)base*3 + idx];
    __syncthreads();
    int p = 0;
    for (; p + 3 < m; p += 4) {
      int sd0 = sndS[base+p+0], sd1 = sndS[base+p+1];
      int sd2 = sndS[base+p+2], sd3 = sndS[base+p+3];
      __half2 g0a = A1h2[(size_t)sd0*NP2 + qg[0]];
      __half2 g1a = A1h2[(size_t)sd1*NP2 + qg[0]];
      __half2 g2a = A1h2[(size_t)sd2*NP2 + qg[0]];
      __half2 g3a = A1h2[(size_t)sd3*NP2 + qg[0]];
      __half2 g0b, g1b, g2b, g3b;
      if (val[1]) {
        g0b = A1h2[(size_t)sd0*NP2 + qg[1]];
        g1b = A1h2[(size_t)sd1*NP2 + qg[1]];
        g2b = A1h2[(size_t)sd2*NP2 + qg[1]];
        g3b = A1h2[(size_t)sd3*NP2 + qg[1]];
      }
      #pragma unroll
      for (int x = 0; x < 4; ++x) {
        const float* e0 = s_e + (p+x)*FW;
        const float* x0 = s_ec + (p+x)*12;
        __half2 ga = (x==0)?g0a:(x==1)?g1a:(x==2)?g2a:g3a;
        {
          float rv = e0[rq[0]];
          float2 gf = __half22float2(ga);
          accA[0][0] += gf.x * rv;
          accA[0][1] += gf.y * rv;
          accB[0][0] += rv * e0[8+i0[0]] * x0[c0[0]];
          accB[0][1] += rv * e0[8+i1[0]] * x0[c1[0]];
        }
        if (val[1]) {
          __half2 gb = (x==0)?g0b:(x==1)?g1b:(x==2)?g2b:g3b;
          float rv = e0[rq[1]];
          float2 gf = __half22float2(gb);
          accA[1][0] += gf.x * rv;
          accA[1][1] += gf.y * rv;
          accB[1][0] += rv * e0[8+i0[1]] * x0[c0[1]];
          accB[1][1] += rv * e0[8+i1[1]] * x0[c1[1]];
        }
      }
    }
    for (; p < m; ++p) {
      int sd = sndS[base+p];
      const float* e0 = s_e + p*FW;
      const float* x0 = s_ec + p*12;
      const __half2* Ah = A1h2 + (size_t)sd*NP2;
      #pragma unroll
      for (int jj = 0; jj < 2; ++jj) {
        if (val[jj]) {
          float rv = e0[rq[jj]];
          float2 gf = __half22float2(Ah[qg[jj]]);
          accA[jj][0] += gf.x * rv;
          accA[jj][1] += gf.y * rv;
          accB[jj][0] += rv * e0[8+i0[jj]] * x0[c0[jj]];
          accB[jj][1] += rv * e0[8+i1[jj]] * x0[c1[jj]];
        }
      }
    }
  }
  __syncthreads();
  float* s_a1 = s_e;   // reuse staging LDS as the A1 tile
  #pragma unroll
  for (int jj = 0; jj < 2; ++jj)
    if (val[jj]) {
      s_tile[rq[jj]*90 + 2*kk[jj]]     = accB[jj][0];
      s_tile[rq[jj]*90 + 2*kk[jj] + 1] = accB[jj][1];
      s_a1[rq[jj]*90 + 2*kk[jj]]       = mymem[jj].x;
      s_a1[rq[jj]*90 + 2*kk[jj] + 1]   = mymem[jj].y;
    }
  __syncthreads();
  float a2v[2][2];
  #pragma unroll
  for (int jj = 0; jj < 2; ++jj) {
    if (val[jj]) {
      float ab0 = 0.f, ab1 = 0.f;
      #pragma unroll
      for (int r = 0; r < NRB; ++r) {
        ab0 += s_tile[r*90 + 2*kk[jj]]     * s_wrt[l0[jj]*64 + r*8 + rq[jj]];
        ab1 += s_tile[r*90 + 2*kk[jj] + 1] * s_wrt[l1[jj]*64 + r*8 + rq[jj]];
      }
      float mem0 = mymem[jj].x * s_wnm[rq[jj]*36 + l0[jj]*9 + c0[jj]];
      float mem1 = mymem[jj].y * s_wnm[rq[jj]*36 + l1[jj]*9 + c1[jj]];
      a2v[jj][0] = (ab0 + accA[jj][0])*MPN + mem0;
      a2v[jj][1] = (ab1 + accA[jj][1])*MPN + mem1;
    }
  }
  __syncthreads();
  #pragma unroll
  for (int jj = 0; jj < 2; ++jj)
    if (val[jj]) {
      s_tile[rq[jj]*90 + 2*kk[jj]]     = a2v[jj][0];
      s_tile[rq[jj]*90 + 2*kk[jj] + 1] = a2v[jj][1];
    }
  __syncthreads();
  // epilogue: b0 from s_a1 (feats0), b1 from s_tile (feats1), paired float2 store
  float2* o2 = (float2*)out;
  if (half == 0) {
    for (int m2 = t; m2 < 288; m2 += 256) {
      int s = m2 / 36, rm = m2 % 36, l5 = rm / 9, c = rm % 9;
      float b0, b1;
      if (l5 == 0) {
        b0 = s_a1[s*90 + c];
        b1 = s_tile[s*90 + c];
      } else {
        b0 = 0.f; b1 = 0.f;
        for (int i = c_GB[l5]; i < c_GE[l5]; ++i) {
          float v0 = s_a1[s*90 + i*9 + c];
          float v1 = s_tile[s*90 + i*9 + c];
          b0 += c_PREF[i]*v0*v0;
          b1 += c_PREF[i]*v1*v1;
        }
      }
      o2[(size_t)((n*8 + s)*5 + l5)*9 + c] = make_float2(b0, b1);
    }
  } else {
    if (t < 72) {
      int s = t / 9, c = t % 9;
      float b0 = 0.f, b1 = 0.f;
      for (int i = 10; i < 20; ++i) {
        float v0 = s_a1[s*90 + (i-10)*9 + c];
        float v1 = s_tile[s*90 + (i-10)*9 + c];
        b0 += c_PREF[i]*v0*v0;
        b1 += c_PREF[i]*v1*v1;
      }
      o2[(size_t)((n*8 + s)*5 + 4)*9 + c] = make_float2(b0, b1);
    }
  }
}

extern "C" void kernel_launch(void* const* d_in, const int* in_sizes, int n_in,
                              void* d_out, int out_size, void* d_ws, size_t ws_size,
                              hipStream_t stream) {
  const float* pos    = (const float*)d_in[0];
  const float* shifts = (const float*)d_in[1];
  const float* W_emb  = (const float*)d_in[2];
  const float* W_rt   = (const float*)d_in[3];
  const float* W_nm   = (const float*)d_in[4];
  const int*   an     = (const int*)d_in[5];
  const int*   ei     = (const int*)d_in[6];
  float* out = (float*)d_out;

  char* ws = (char*)d_ws;
  size_t off = 0;
  auto carve = [&](size_t bytes) {
    void* p = ws + off;
    off = (off + bytes + 255) & ~(size_t)255;
    return p;
  };
  float*   facS    = (float*)carve((size_t)FW*NEDGE*sizeof(float));
  int*     sndS    = (int*)carve((size_t)NEDGE*sizeof(int));
  float*   echiS   = (float*)carve((size_t)12*NEDGE*sizeof(float));
  float2*  A1f2    = (float2*)carve((size_t)NNODE*NEL*sizeof(float));
  __half2* A1h2    = (__half2*)carve((size_t)NNODE*NEL*sizeof(__half));
  float*   chi     = (float*)carve((size_t)NNODE*NCH*sizeof(float));
  int*     counts  = (int*)carve((size_t)NNODE*sizeof(int));
  int*     offsets = (int*)carve((size_t)(NNODE+1)*sizeof(int));
  int*     cursor  = (int*)carve((size_t)NNODE*sizeof(int));

  size_t z0 = (size_t)((char*)chi - ws);
  size_t z1 = (size_t)((char*)counts - ws) + (size_t)NNODE*sizeof(int);
  hipMemsetAsync((char*)ws + z0, 0, z1 - z0, stream);
  k_count<<<(NEDGE+255)/256, 256, 0, stream>>>(ei, counts);
  k_scan<<<1, 1024, 0, stream>>>(counts, offsets, cursor);
  k_edgec<<<(NEDGE+255)/256, 256, 0, stream>>>(pos, shifts, ei, an, W_emb, cursor, facS, sndS);
  k_nodeA<<<NNODE*2, 256, 0, stream>>>(facS, offsets, W_rt, A1f2, A1h2, chi);
  k_echi<<<(NEDGE+255)/256, 256, 0, stream>>>(facS, sndS, chi, echiS);
  k_nodeMP<<<NNODE*2, 256, 0, stream>>>(facS, offsets, sndS, echiS, W_rt, W_nm, A1f2, A1h2, out);
}

// Round 12
// 116.963 us; speedup vs baseline: 1.4166x; 1.0222x over previous
//
#include <hip/hip_runtime.h>
#include <hip/hip_fp16.h>

#ifndef M_PIf
#define M_PIf 3.14159265358979323846f
#endif

constexpr int NNODE = 4000;
constexpr int NEDGE = 48000;
constexpr int NLA   = 20;
constexpr int NCH   = 9;
constexpr int NRB   = 8;
constexpr int NEL   = NRB * NLA * NCH;    // 1440
constexpr int NP2   = NEL / 2;            // 720 half2 pairs
constexpr int FW    = 40;                 // facS row width (floats)
constexpr int EC    = 32;                 // edge chunk per LDS stage
constexpr float CUT = 5.5f;
constexpr float MPN = 0.316227766016837933f;

__constant__ int   c_LOF[NLA]  = {0,1,1,1,2,2,2,2,2,2,3,3,3,3,3,3,3,3,3,3};
__constant__ float c_PREF[NLA] = {1,1,1,1,1,2,2,1,2,1,1,3,3,3,6,3,1,3,3,1};
__constant__ int   c_GB[4] = {0,0,1,4};
__constant__ int   c_GE[4] = {0,1,4,10};

__global__ void k_count(const int* __restrict__ ei, int* __restrict__ counts) {
  int e = blockIdx.x * blockDim.x + threadIdx.x;
  if (e >= NEDGE) return;
  atomicAdd(&counts[ei[NEDGE + e]], 1);
}

__global__ void k_scan(const int* __restrict__ counts, int* __restrict__ offsets,
                       int* __restrict__ cursor) {
  __shared__ int wsum[16];
  int t = threadIdx.x;
  int base = t*4;
  int c0 = (base+0 < NNODE) ? counts[base+0] : 0;
  int c1 = (base+1 < NNODE) ? counts[base+1] : 0;
  int c2 = (base+2 < NNODE) ? counts[base+2] : 0;
  int c3 = (base+3 < NNODE) ? counts[base+3] : 0;
  int s = c0+c1+c2+c3;
  int lane = t & 63, w = t >> 6;
  int incl = s;
  #pragma unroll
  for (int d = 1; d < 64; d <<= 1) {
    int v = __shfl_up(incl, d);
    if (lane >= d) incl += v;
  }
  if (lane == 63) wsum[w] = incl;
  __syncthreads();
  if (t < 16) {
    int v = wsum[t];
    int inc2 = v;
    #pragma unroll
    for (int d = 1; d < 16; d <<= 1) {
      int u = __shfl_up(inc2, d);
      if (t >= d) inc2 += u;
    }
    wsum[t] = inc2 - v;   // exclusive wave prefix
  }
  __syncthreads();
  int excl = wsum[w] + incl - s;
  int o0 = excl, o1 = o0+c0, o2 = o1+c1, o3 = o2+c2;
  if (base+0 < NNODE) { offsets[base+0]=o0; cursor[base+0]=o0; }
  if (base+1 < NNODE) { offsets[base+1]=o1; cursor[base+1]=o1; }
  if (base+2 < NNODE) { offsets[base+2]=o2; cursor[base+2]=o2; }
  if (base+3 < NNODE) { offsets[base+3]=o3; cursor[base+3]=o3; }
  if (t == 1023) offsets[NNODE] = excl + s;
}

__global__ void k_edgec(const float* __restrict__ pos, const float* __restrict__ shifts,
                        const int* __restrict__ ei, const int* __restrict__ an,
                        const float* __restrict__ W_emb,
                        int* __restrict__ cursor, float* __restrict__ facS,
                        int* __restrict__ sndS) {
  int e = blockIdx.x * blockDim.x + threadIdx.x;
  if (e >= NEDGE) return;
  int snd = ei[e];
  int rcv = ei[NEDGE + e];
  float vx = pos[rcv*3+0] - pos[snd*3+0] + shifts[e*3+0];
  float vy = pos[rcv*3+1] - pos[snd*3+1] + shifts[e*3+1];
  float vz = pos[rcv*3+2] - pos[snd*3+2] + shifts[e*3+2];
  float len = sqrtf(vx*vx + vy*vy + vz*vz);
  float inv = 1.0f / len;
  float x = vx*inv, y = vy*inv, z = vz*inv;
  float u  = len * (1.0f/CUT);
  float u2 = u*u;
  float u6 = u2*u2*u2;
  float fcut = 1.0f - 28.0f*u6 + 48.0f*u6*u - 21.0f*u6*u2;
  if (u >= 1.0f) fcut = 0.0f;
  float pre = sqrtf(2.0f/CUT) * fcut * inv;
  int p = atomicAdd(&cursor[rcv], 1);
  float* f = facS + (size_t)p*FW;
  // sin(n*pi*u) via Chebyshev recurrence: 1 sin + 1 cos + FMAs
  float s1 = __sinf(M_PIf * u);
  float cth = __cosf(M_PIf * u);
  float two_c = 2.0f * cth;
  float sm1 = 0.0f, sc = s1;
  #pragma unroll
  for (int j = 0; j < NRB; ++j) {
    f[j] = pre * sc;
    float nx = two_c * sc - sm1;
    sm1 = sc; sc = nx;
  }
  float ang[NLA];
  ang[0]=1.0f; ang[1]=x; ang[2]=y; ang[3]=z;
  ang[4]=x*x; ang[5]=x*y; ang[6]=x*z; ang[7]=y*y; ang[8]=y*z; ang[9]=z*z;
  ang[10]=ang[4]*x; ang[11]=ang[4]*y; ang[12]=ang[4]*z;
  ang[13]=x*ang[7]; ang[14]=ang[5]*z; ang[15]=x*ang[9];
  ang[16]=ang[7]*y; ang[17]=ang[7]*z; ang[18]=y*ang[9]; ang[19]=ang[9]*z;
  #pragma unroll
  for (int i = 0; i < NLA; ++i) f[8+i] = ang[i];
  int as_ = an[snd], ar_ = an[rcv];
  int sps = (as_==1)?0:(as_==6)?1:(as_==7)?2:3;
  int spr = (ar_==1)?0:(ar_==6)?1:(ar_==7)?2:3;
  float es0=W_emb[sps*3+0], es1=W_emb[sps*3+1], es2=W_emb[sps*3+2];
  float er0=W_emb[spr*3+0], er1=W_emb[spr*3+1], er2=W_emb[spr*3+2];
  f[28]=es0*er0; f[29]=es0*er1; f[30]=es0*er2;
  f[31]=es1*er0; f[32]=es1*er1; f[33]=es1*er2;
  f[34]=es2*er0; f[35]=es2*er1; f[36]=es2*er2;
  f[37]=0.f; f[38]=0.f; f[39]=0.f;
  sndS[p] = snd;
}

// In-place: facS[p][28..36] = chi[snd_p] * enc_p  (k_nodeA consumed enc already)
__global__ void k_echi(float* __restrict__ facS, const int* __restrict__ sndS,
                       const float* __restrict__ chi) {
  int p = blockIdx.x * blockDim.x + threadIdx.x;
  if (p >= NEDGE) return;
  int snd = sndS[p];
  float* f = facS + (size_t)p*FW;
  #pragma unroll
  for (int c = 0; c < 9; ++c)
    f[28 + c] = chi[snd*9 + c] * f[28 + c];
}

// ---- split-node kernels: block = (node,half);
// pair slot j in [0,360): r = j/45, kk = j%45; global half2-pair q = r*90+kk+45*half
// j0 = t (valid always), j1 = t+256 (valid t<104)

__global__ __launch_bounds__(256, 8) void k_nodeA(
    const float* __restrict__ facS, const int* __restrict__ offsets,
    const float* __restrict__ W_rt,
    float2* __restrict__ A1f2, __half2* __restrict__ A1h2,
    float* __restrict__ chi) {
  __shared__ float s_wrt[256];
  __shared__ float s_e[EC*FW];
  __shared__ float s_tile[8*90];
  __shared__ float s_B[288];
  int bid = blockIdx.x;
  int n = bid >> 1, half = bid & 1;
  int t = threadIdx.x;
  s_wrt[t] = W_rt[t];
  int rq[2], kk[2], i0[2], c0[2], l0[2], i1[2], c1[2], l1[2], qg[2];
  bool val[2];
  #pragma unroll
  for (int jj = 0; jj < 2; ++jj) {
    int j = t + jj*256;
    val[jj] = (j < 360);
    int js = val[jj] ? j : 0;
    rq[jj] = js / 45; kk[jj] = js % 45;
    qg[jj] = rq[jj]*90 + kk[jj] + half*45;
    int rem0 = 2*(kk[jj] + 45*half);
    i0[jj] = rem0 / 9;  c0[jj] = rem0 % 9;  l0[jj] = c_LOF[i0[jj]];
    int rem1 = rem0 + 1;
    i1[jj] = rem1 / 9;  c1[jj] = rem1 % 9;  l1[jj] = c_LOF[i1[jj]];
  }
  float acc[2][2] = {{0,0},{0,0}};
  int beg = offsets[n], end = offsets[n+1];
  const float4* f4 = (const float4*)facS;
  for (int base = beg; base < end; base += EC) {
    int m = min(EC, end - base);
    if (base != beg) __syncthreads();
    for (int idx = t; idx < m*(FW/4); idx += 256)
      ((float4*)s_e)[idx] = f4[(size_t)base*(FW/4) + idx];
    __syncthreads();
    for (int p = 0; p < m; ++p) {
      const float* e0 = s_e + p*FW;
      #pragma unroll
      for (int jj = 0; jj < 2; ++jj) {
        if (val[jj]) {
          float rv = e0[rq[jj]];
          acc[jj][0] += rv * e0[8+i0[jj]] * e0[28+c0[jj]];
          acc[jj][1] += rv * e0[8+i1[jj]] * e0[28+c1[jj]];
        }
      }
    }
  }
  __syncthreads();
  #pragma unroll
  for (int jj = 0; jj < 2; ++jj)
    if (val[jj]) {
      s_tile[rq[jj]*90 + 2*kk[jj]]     = acc[jj][0];
      s_tile[rq[jj]*90 + 2*kk[jj] + 1] = acc[jj][1];
    }
  __syncthreads();
  float a1v[2][2];
  #pragma unroll
  for (int jj = 0; jj < 2; ++jj) {
    if (val[jj]) {
      float ab0 = 0.f, ab1 = 0.f;
      #pragma unroll
      for (int r = 0; r < NRB; ++r) {
        ab0 += s_tile[r*90 + 2*kk[jj]]     * s_wrt[l0[jj]*64 + r*8 + rq[jj]];
        ab1 += s_tile[r*90 + 2*kk[jj] + 1] * s_wrt[l1[jj]*64 + r*8 + rq[jj]];
      }
      a1v[jj][0] = ab0; a1v[jj][1] = ab1;
      size_t qi = (size_t)n*NP2 + qg[jj];
      A1f2[qi] = make_float2(ab0, ab1);
      A1h2[qi] = __floats2half2_rn(ab0, ab1);
    }
  }
  __syncthreads();
  #pragma unroll
  for (int jj = 0; jj < 2; ++jj)
    if (val[jj]) {
      s_tile[rq[jj]*90 + 2*kk[jj]]     = a1v[jj][0];
      s_tile[rq[jj]*90 + 2*kk[jj] + 1] = a1v[jj][1];
    }
  __syncthreads();
  // chi only (feats written by k_nodeMP as float2)
  if (half == 0) {
    for (int m2 = t; m2 < 288; m2 += 256) {
      int s = m2 / 36, rm = m2 % 36, l5 = rm / 9, c = rm % 9;
      float b;
      if (l5 == 0) b = s_tile[s*90 + c];
      else {
        b = 0.f;
        for (int i = c_GB[l5]; i < c_GE[l5]; ++i) {
          float v = s_tile[s*90 + i*9 + c];
          b += c_PREF[i]*v*v;
        }
      }
      s_B[m2] = b;
    }
    __syncthreads();
    if (t < 9) {
      float x = 0.f;
      #pragma unroll
      for (int u = 0; u < 32; ++u) x += s_B[u*9 + t];
      atomicAdd(&chi[n*9 + t], x);
    }
  } else {
    if (t < 72) {
      int s = t / 9, c = t % 9;
      float b = 0.f;
      for (int i = 10; i < 20; ++i) {
        float v = s_tile[s*90 + (i-10)*9 + c];
        b += c_PREF[i]*v*v;
      }
      s_B[t] = b;
    }
    __syncthreads();
    if (t < 9) {
      float x = 0.f;
      #pragma unroll
      for (int u = 0; u < 8; ++u) x += s_B[u*9 + t];
      atomicAdd(&chi[n*9 + t], x);
    }
  }
}

__global__ __launch_bounds__(256, 8) void k_nodeMP(
    const float* __restrict__ facS, const int* __restrict__ offsets,
    const int* __restrict__ sndS,
    const float* __restrict__ W_rt, const float* __restrict__ W_nm,
    const float2* __restrict__ A1f2, const __half2* __restrict__ A1h2,
    float* __restrict__ out) {
  __shared__ float s_wrt[256];
  __shared__ float s_wnm[288];
  __shared__ float s_e[EC*FW];     // reused as a1 tile (720 floats) in epilogue
  __shared__ float s_tile[8*90];
  int bid = blockIdx.x;
  int n = bid >> 1, half = bid & 1;
  int t = threadIdx.x;
  s_wrt[t] = W_rt[t];
  s_wnm[t] = W_nm[t];
  if (t < 32) s_wnm[256 + t] = W_nm[256 + t];
  int rq[2], kk[2], i0[2], c0[2], l0[2], i1[2], c1[2], l1[2], qg[2];
  bool val[2];
  #pragma unroll
  for (int jj = 0; jj < 2; ++jj) {
    int j = t + jj*256;
    val[jj] = (j < 360);
    int js = val[jj] ? j : 0;
    rq[jj] = js / 45; kk[jj] = js % 45;
    qg[jj] = rq[jj]*90 + kk[jj] + half*45;
    int rem0 = 2*(kk[jj] + 45*half);
    i0[jj] = rem0 / 9;  c0[jj] = rem0 % 9;  l0[jj] = c_LOF[i0[jj]];
    int rem1 = rem0 + 1;
    i1[jj] = rem1 / 9;  c1[jj] = rem1 % 9;  l1[jj] = c_LOF[i1[jj]];
  }
  float accA[2][2] = {{0,0},{0,0}};
  float accB[2][2] = {{0,0},{0,0}};
  float2 mymem[2];
  #pragma unroll
  for (int jj = 0; jj < 2; ++jj)
    mymem[jj] = val[jj] ? A1f2[(size_t)n*NP2 + qg[jj]] : make_float2(0.f, 0.f);
  int beg = offsets[n], end = offsets[n+1];
  const float4* f4 = (const float4*)facS;
  for (int base = beg; base < end; base += EC) {
    int m = min(EC, end - base);
    if (base != beg) __syncthreads();
    for (int idx = t; idx < m*(FW/4); idx += 256)
      ((float4*)s_e)[idx] = f4[(size_t)base*(FW/4) + idx];
    __syncthreads();
    int p = 0;
    for (; p + 3 < m; p += 4) {
      int sd0 = sndS[base+p+0], sd1 = sndS[base+p+1];
      int sd2 = sndS[base+p+2], sd3 = sndS[base+p+3];
      __half2 g0a = A1h2[(size_t)sd0*NP2 + qg[0]];
      __half2 g1a = A1h2[(size_t)sd1*NP2 + qg[0]];
      __half2 g2a = A1h2[(size_t)sd2*NP2 + qg[0]];
      __half2 g3a = A1h2[(size_t)sd3*NP2 + qg[0]];
      __half2 g0b, g1b, g2b, g3b;
      if (val[1]) {
        g0b = A1h2[(size_t)sd0*NP2 + qg[1]];
        g1b = A1h2[(size_t)sd1*NP2 + qg[1]];
        g2b = A1h2[(size_t)sd2*NP2 + qg[1]];
        g3b = A1h2[(size_t)sd3*NP2 + qg[1]];
      }
      #pragma unroll
      for (int x = 0; x < 4; ++x) {
        const float* e0 = s_e + (p+x)*FW;
        const float* x0 = e0 + 28;          // chi*enc (in-place from k_echi)
        __half2 ga = (x==0)?g0a:(x==1)?g1a:(x==2)?g2a:g3a;
        {
          float rv = e0[rq[0]];
          float2 gf = __half22float2(ga);
          accA[0][0] += gf.x * rv;
          accA[0][1] += gf.y * rv;
          accB[0][0] += rv * e0[8+i0[0]] * x0[c0[0]];
          accB[0][1] += rv * e0[8+i1[0]] * x0[c1[0]];
        }
        if (val[1]) {
          __half2 gb = (x==0)?g0b:(x==1)?g1b:(x==2)?g2b:g3b;
          float rv = e0[rq[1]];
          float2 gf = __half22float2(gb);
          accA[1][0] += gf.x * rv;
          accA[1][1] += gf.y * rv;
          accB[1][0] += rv * e0[8+i0[1]] * x0[c0[1]];
          accB[1][1] += rv * e0[8+i1[1]] * x0[c1[1]];
        }
      }
    }
    for (; p < m; ++p) {
      int sd = sndS[base+p];
      const float* e0 = s_e + p*FW;
      const float* x0 = e0 + 28;
      const __half2* Ah = A1h2 + (size_t)sd*NP2;
      #pragma unroll
      for (int jj = 0; jj < 2; ++jj) {
        if (val[jj]) {
          float rv = e0[rq[jj]];
          float2 gf = __half22float2(Ah[qg[jj]]);
          accA[jj][0] += gf.x * rv;
          accA[jj][1] += gf.y * rv;
          accB[jj][0] += rv * e0[8+i0[jj]] * x0[c0[jj]];
          accB[jj][1] += rv * e0[8+i1[jj]] * x0[c1[jj]];
        }
      }
    }
  }
  __syncthreads();
  float* s_a1 = s_e;   // reuse staging LDS as the A1 tile
  #pragma unroll
  for (int jj = 0; jj < 2; ++jj)
    if (val[jj]) {
      s_tile[rq[jj]*90 + 2*kk[jj]]     = accB[jj][0];
      s_tile[rq[jj]*90 + 2*kk[jj] + 1] = accB[jj][1];
      s_a1[rq[jj]*90 + 2*kk[jj]]       = mymem[jj].x;
      s_a1[rq[jj]*90 + 2*kk[jj] + 1]   = mymem[jj].y;
    }
  __syncthreads();
  float a2v[2][2];
  #pragma unroll
  for (int jj = 0; jj < 2; ++jj) {
    if (val[jj]) {
      float ab0 = 0.f, ab1 = 0.f;
      #pragma unroll
      for (int r = 0; r < NRB; ++r) {
        ab0 += s_tile[r*90 + 2*kk[jj]]     * s_wrt[l0[jj]*64 + r*8 + rq[jj]];
        ab1 += s_tile[r*90 + 2*kk[jj] + 1] * s_wrt[l1[jj]*64 + r*8 + rq[jj]];
      }
      float mem0 = mymem[jj].x * s_wnm[rq[jj]*36 + l0[jj]*9 + c0[jj]];
      float mem1 = mymem[jj].y * s_wnm[rq[jj]*36 + l1[jj]*9 + c1[jj]];
      a2v[jj][0] = (ab0 + accA[jj][0])*MPN + mem0;
      a2v[jj][1] = (ab1 + accA[jj][1])*MPN + mem1;
    }
  }
  __syncthreads();
  #pragma unroll
  for (int jj = 0; jj < 2; ++jj)
    if (val[jj]) {
      s_tile[rq[jj]*90 + 2*kk[jj]]     = a2v[jj][0];
      s_tile[rq[jj]*90 + 2*kk[jj] + 1] = a2v[jj][1];
    }
  __syncthreads();
  // epilogue: b0 from s_a1 (feats0), b1 from s_tile (feats1), paired float2 store
  float2* o2 = (float2*)out;
  if (half == 0) {
    for (int m2 = t; m2 < 288; m2 += 256) {
      int s = m2 / 36, rm = m2 % 36, l5 = rm / 9, c = rm % 9;
      float b0, b1;
      if (l5 == 0) {
        b0 = s_a1[s*90 + c];
        b1 = s_tile[s*90 + c];
      } else {
        b0 = 0.f; b1 = 0.f;
        for (int i = c_GB[l5]; i < c_GE[l5]; ++i) {
          float v0 = s_a1[s*90 + i*9 + c];
          float v1 = s_tile[s*90 + i*9 + c];
          b0 += c_PREF[i]*v0*v0;
          b1 += c_PREF[i]*v1*v1;
        }
      }
      o2[(size_t)((n*8 + s)*5 + l5)*9 + c] = make_float2(b0, b1);
    }
  } else {
    if (t < 72) {
      int s = t / 9, c = t % 9;
      float b0 = 0.f, b1 = 0.f;
      for (int i = 10; i < 20; ++i) {
        float v0 = s_a1[s*90 + (i-10)*9 + c];
        float v1 = s_tile[s*90 + (i-10)*9 + c];
        b0 += c_PREF[i]*v0*v0;
        b1 += c_PREF[i]*v1*v1;
      }
      o2[(size_t)((n*8 + s)*5 + 4)*9 + c] = make_float2(b0, b1);
    }
  }
}

extern "C" void kernel_launch(void* const* d_in, const int* in_sizes, int n_in,
                              void* d_out, int out_size, void* d_ws, size_t ws_size,
                              hipStream_t stream) {
  const float* pos    = (const float*)d_in[0];
  const float* shifts = (const float*)d_in[1];
  const float* W_emb  = (const float*)d_in[2];
  const float* W_rt   = (const float*)d_in[3];
  const float* W_nm   = (const float*)d_in[4];
  const int*   an     = (const int*)d_in[5];
  const int*   ei     = (const int*)d_in[6];
  float* out = (float*)d_out;

  char* ws = (char*)d_ws;
  size_t off = 0;
  auto carve = [&](size_t bytes) {
    void* p = ws + off;
    off = (off + bytes + 255) & ~(size_t)255;
    return p;
  };
  float*   facS    = (float*)carve((size_t)FW*NEDGE*sizeof(float));
  int*     sndS    = (int*)carve((size_t)NEDGE*sizeof(int));
  float2*  A1f2    = (float2*)carve((size_t)NNODE*NEL*sizeof(float));
  __half2* A1h2    = (__half2*)carve((size_t)NNODE*NEL*sizeof(__half));
  float*   chi     = (float*)carve((size_t)NNODE*NCH*sizeof(float));
  int*     counts  = (int*)carve((size_t)NNODE*sizeof(int));
  int*     offsets = (int*)carve((size_t)(NNODE+1)*sizeof(int));
  int*     cursor  = (int*)carve((size_t)NNODE*sizeof(int));

  size_t z0 = (size_t)((char*)chi - ws);
  size_t z1 = (size_t)((char*)counts - ws) + (size_t)NNODE*sizeof(int);
  hipMemsetAsync((char*)ws + z0, 0, z1 - z0, stream);
  k_count<<<(NEDGE+255)/256, 256, 0, stream>>>(ei, counts);
  k_scan<<<1, 1024, 0, stream>>>(counts, offsets, cursor);
  k_edgec<<<(NEDGE+255)/256, 256, 0, stream>>>(pos, shifts, ei, an, W_emb, cursor, facS, sndS);
  k_nodeA<<<NNODE*2, 256, 0, stream>>>(facS, offsets, W_rt, A1f2, A1h2, chi);
  k_echi<<<(NEDGE+255)/256, 256, 0, stream>>>(facS, sndS, chi);
  k_nodeMP<<<NNODE*2, 256, 0, stream>>>(facS, offsets, sndS, W_rt, W_nm, A1f2, A1h2, out);
}

// Round 13
// 115.039 us; speedup vs baseline: 1.4403x; 1.0167x over previous
//
#include <hip/hip_runtime.h>
#include <hip/hip_fp16.h>

#ifndef M_PIf
#define M_PIf 3.14159265358979323846f
#endif

constexpr int NNODE = 4000;
constexpr int NEDGE = 48000;
constexpr int NLA   = 20;
constexpr int NCH   = 9;
constexpr int NRB   = 8;
constexpr int NEL   = NRB * NLA * NCH;    // 1440
constexpr int NP2   = NEL / 2;            // 720 half2 pairs
constexpr int FW    = 40;                 // facS row width (floats)
constexpr int EC    = 32;                 // edge chunk per LDS stage
constexpr float CUT = 5.5f;
constexpr float MPN = 0.316227766016837933f;

__constant__ int   c_LOF[NLA]  = {0,1,1,1,2,2,2,2,2,2,3,3,3,3,3,3,3,3,3,3};
__constant__ float c_PREF[NLA] = {1,1,1,1,1,2,2,1,2,1,1,3,3,3,6,3,1,3,3,1};
__constant__ int   c_GB[4] = {0,0,1,4};
__constant__ int   c_GE[4] = {0,1,4,10};

__global__ void k_count(const int* __restrict__ ei, int* __restrict__ counts) {
  int e = blockIdx.x * blockDim.x + threadIdx.x;
  if (e >= NEDGE) return;
  atomicAdd(&counts[ei[NEDGE + e]], 1);
}

__global__ void k_scan(const int* __restrict__ counts, int* __restrict__ offsets,
                       int* __restrict__ cursor) {
  __shared__ int wsum[16];
  int t = threadIdx.x;
  int base = t*4;
  int c0 = (base+0 < NNODE) ? counts[base+0] : 0;
  int c1 = (base+1 < NNODE) ? counts[base+1] : 0;
  int c2 = (base+2 < NNODE) ? counts[base+2] : 0;
  int c3 = (base+3 < NNODE) ? counts[base+3] : 0;
  int s = c0+c1+c2+c3;
  int lane = t & 63, w = t >> 6;
  int incl = s;
  #pragma unroll
  for (int d = 1; d < 64; d <<= 1) {
    int v = __shfl_up(incl, d);
    if (lane >= d) incl += v;
  }
  if (lane == 63) wsum[w] = incl;
  __syncthreads();
  if (t < 16) {
    int v = wsum[t];
    int inc2 = v;
    #pragma unroll
    for (int d = 1; d < 16; d <<= 1) {
      int u = __shfl_up(inc2, d);
      if (t >= d) inc2 += u;
    }
    wsum[t] = inc2 - v;   // exclusive wave prefix
  }
  __syncthreads();
  int excl = wsum[w] + incl - s;
  int o0 = excl, o1 = o0+c0, o2 = o1+c1, o3 = o2+c2;
  if (base+0 < NNODE) { offsets[base+0]=o0; cursor[base+0]=o0; }
  if (base+1 < NNODE) { offsets[base+1]=o1; cursor[base+1]=o1; }
  if (base+2 < NNODE) { offsets[base+2]=o2; cursor[base+2]=o2; }
  if (base+3 < NNODE) { offsets[base+3]=o3; cursor[base+3]=o3; }
  if (t == 1023) offsets[NNODE] = excl + s;
}

__global__ void k_edgec(const float* __restrict__ pos, const float* __restrict__ shifts,
                        const int* __restrict__ ei, const int* __restrict__ an,
                        const float* __restrict__ W_emb,
                        int* __restrict__ cursor, float* __restrict__ facS,
                        int* __restrict__ sndS) {
  int e = blockIdx.x * blockDim.x + threadIdx.x;
  if (e >= NEDGE) return;
  int snd = ei[e];
  int rcv = ei[NEDGE + e];
  float vx = pos[rcv*3+0] - pos[snd*3+0] + shifts[e*3+0];
  float vy = pos[rcv*3+1] - pos[snd*3+1] + shifts[e*3+1];
  float vz = pos[rcv*3+2] - pos[snd*3+2] + shifts[e*3+2];
  float len = sqrtf(vx*vx + vy*vy + vz*vz);
  float inv = 1.0f / len;
  float x = vx*inv, y = vy*inv, z = vz*inv;
  float u  = len * (1.0f/CUT);
  float u2 = u*u;
  float u6 = u2*u2*u2;
  float fcut = 1.0f - 28.0f*u6 + 48.0f*u6*u - 21.0f*u6*u2;
  if (u >= 1.0f) fcut = 0.0f;
  float pre = sqrtf(2.0f/CUT) * fcut * inv;
  int p = atomicAdd(&cursor[rcv], 1);
  float* f = facS + (size_t)p*FW;
  // sin(n*pi*u) via Chebyshev recurrence: 1 sin + 1 cos + FMAs
  float s1 = __sinf(M_PIf * u);
  float cth = __cosf(M_PIf * u);
  float two_c = 2.0f * cth;
  float sm1 = 0.0f, sc = s1;
  #pragma unroll
  for (int j = 0; j < NRB; ++j) {
    f[j] = pre * sc;
    float nx = two_c * sc - sm1;
    sm1 = sc; sc = nx;
  }
  float ang[NLA];
  ang[0]=1.0f; ang[1]=x; ang[2]=y; ang[3]=z;
  ang[4]=x*x; ang[5]=x*y; ang[6]=x*z; ang[7]=y*y; ang[8]=y*z; ang[9]=z*z;
  ang[10]=ang[4]*x; ang[11]=ang[4]*y; ang[12]=ang[4]*z;
  ang[13]=x*ang[7]; ang[14]=ang[5]*z; ang[15]=x*ang[9];
  ang[16]=ang[7]*y; ang[17]=ang[7]*z; ang[18]=y*ang[9]; ang[19]=ang[9]*z;
  #pragma unroll
  for (int i = 0; i < NLA; ++i) f[8+i] = ang[i];
  int as_ = an[snd], ar_ = an[rcv];
  int sps = (as_==1)?0:(as_==6)?1:(as_==7)?2:3;
  int spr = (ar_==1)?0:(ar_==6)?1:(ar_==7)?2:3;
  float es0=W_emb[sps*3+0], es1=W_emb[sps*3+1], es2=W_emb[sps*3+2];
  float er0=W_emb[spr*3+0], er1=W_emb[spr*3+1], er2=W_emb[spr*3+2];
  f[28]=es0*er0; f[29]=es0*er1; f[30]=es0*er2;
  f[31]=es1*er0; f[32]=es1*er1; f[33]=es1*er2;
  f[34]=es2*er0; f[35]=es2*er1; f[36]=es2*er2;
  f[37]=0.f; f[38]=0.f; f[39]=0.f;
  sndS[p] = snd;
}

// In-place: facS[p][28..36] = chi[snd_p] * enc_p  (k_nodeA consumed enc already)
__global__ void k_echi(float* __restrict__ facS, const int* __restrict__ sndS,
                       const float* __restrict__ chi) {
  int p = blockIdx.x * blockDim.x + threadIdx.x;
  if (p >= NEDGE) return;
  int snd = sndS[p];
  float* f = facS + (size_t)p*FW;
  #pragma unroll
  for (int c = 0; c < 9; ++c)
    f[28 + c] = chi[snd*9 + c] * f[28 + c];
}

// ---- split-node kernels: block = (node,half);
// pair slot j in [0,360): r = j/45, kk = j%45; global half2-pair q = r*90+kk+45*half
// j0 = t (valid always), j1 = t+256 (valid t<104)

__global__ __launch_bounds__(256, 8) void k_nodeA(
    const float* __restrict__ facS, const int* __restrict__ offsets,
    const float* __restrict__ W_rt,
    __half2* __restrict__ A1h2,
    float* __restrict__ chi) {
  __shared__ float s_wrt[256];
  __shared__ float s_e[EC*FW];
  __shared__ float s_tile[8*90];
  __shared__ float s_B[288];
  int bid = blockIdx.x;
  int n = bid >> 1, half = bid & 1;
  int t = threadIdx.x;
  s_wrt[t] = W_rt[t];
  int rq[2], kk[2], i0[2], c0[2], l0[2], i1[2], c1[2], l1[2], qg[2];
  bool val[2];
  #pragma unroll
  for (int jj = 0; jj < 2; ++jj) {
    int j = t + jj*256;
    val[jj] = (j < 360);
    int js = val[jj] ? j : 0;
    rq[jj] = js / 45; kk[jj] = js % 45;
    qg[jj] = rq[jj]*90 + kk[jj] + half*45;
    int rem0 = 2*(kk[jj] + 45*half);
    i0[jj] = rem0 / 9;  c0[jj] = rem0 % 9;  l0[jj] = c_LOF[i0[jj]];
    int rem1 = rem0 + 1;
    i1[jj] = rem1 / 9;  c1[jj] = rem1 % 9;  l1[jj] = c_LOF[i1[jj]];
  }
  float acc[2][2] = {{0,0},{0,0}};
  int beg = offsets[n], end = offsets[n+1];
  const float4* f4 = (const float4*)facS;
  for (int base = beg; base < end; base += EC) {
    int m = min(EC, end - base);
    if (base != beg) __syncthreads();
    for (int idx = t; idx < m*(FW/4); idx += 256)
      ((float4*)s_e)[idx] = f4[(size_t)base*(FW/4) + idx];
    __syncthreads();
    for (int p = 0; p < m; ++p) {
      const float* e0 = s_e + p*FW;
      #pragma unroll
      for (int jj = 0; jj < 2; ++jj) {
        if (val[jj]) {
          float rv = e0[rq[jj]];
          acc[jj][0] += rv * e0[8+i0[jj]] * e0[28+c0[jj]];
          acc[jj][1] += rv * e0[8+i1[jj]] * e0[28+c1[jj]];
        }
      }
    }
  }
  __syncthreads();
  #pragma unroll
  for (int jj = 0; jj < 2; ++jj)
    if (val[jj]) {
      s_tile[rq[jj]*90 + 2*kk[jj]]     = acc[jj][0];
      s_tile[rq[jj]*90 + 2*kk[jj] + 1] = acc[jj][1];
    }
  __syncthreads();
  float a1v[2][2];
  #pragma unroll
  for (int jj = 0; jj < 2; ++jj) {
    if (val[jj]) {
      float ab0 = 0.f, ab1 = 0.f;
      #pragma unroll
      for (int r = 0; r < NRB; ++r) {
        ab0 += s_tile[r*90 + 2*kk[jj]]     * s_wrt[l0[jj]*64 + r*8 + rq[jj]];
        ab1 += s_tile[r*90 + 2*kk[jj] + 1] * s_wrt[l1[jj]*64 + r*8 + rq[jj]];
      }
      a1v[jj][0] = ab0; a1v[jj][1] = ab1;
      A1h2[(size_t)n*NP2 + qg[jj]] = __floats2half2_rn(ab0, ab1);
    }
  }
  __syncthreads();
  #pragma unroll
  for (int jj = 0; jj < 2; ++jj)
    if (val[jj]) {
      s_tile[rq[jj]*90 + 2*kk[jj]]     = a1v[jj][0];
      s_tile[rq[jj]*90 + 2*kk[jj] + 1] = a1v[jj][1];
    }
  __syncthreads();
  // chi only (feats written by k_nodeMP as float2)
  if (half == 0) {
    for (int m2 = t; m2 < 288; m2 += 256) {
      int s = m2 / 36, rm = m2 % 36, l5 = rm / 9, c = rm % 9;
      float b;
      if (l5 == 0) b = s_tile[s*90 + c];
      else {
        b = 0.f;
        for (int i = c_GB[l5]; i < c_GE[l5]; ++i) {
          float v = s_tile[s*90 + i*9 + c];
          b += c_PREF[i]*v*v;
        }
      }
      s_B[m2] = b;
    }
    __syncthreads();
    if (t < 9) {
      float x = 0.f;
      #pragma unroll
      for (int u = 0; u < 32; ++u) x += s_B[u*9 + t];
      atomicAdd(&chi[n*9 + t], x);
    }
  } else {
    if (t < 72) {
      int s = t / 9, c = t % 9;
      float b = 0.f;
      for (int i = 10; i < 20; ++i) {
        float v = s_tile[s*90 + (i-10)*9 + c];
        b += c_PREF[i]*v*v;
      }
      s_B[t] = b;
    }
    __syncthreads();
    if (t < 9) {
      float x = 0.f;
      #pragma unroll
      for (int u = 0; u < 8; ++u) x += s_B[u*9 + t];
      atomicAdd(&chi[n*9 + t], x);
    }
  }
}

__global__ __launch_bounds__(256, 8) void k_nodeMP(
    const float* __restrict__ facS, const int* __restrict__ offsets,
    const int* __restrict__ sndS,
    const float* __restrict__ W_rt, const float* __restrict__ W_nm,
    const __half2* __restrict__ A1h2,
    float* __restrict__ out) {
  __shared__ float s_wrt[256];
  __shared__ float s_wnm[288];
  __shared__ float s_e[EC*FW];     // reused as a1 tile (720 floats) in epilogue
  __shared__ float s_tile[8*90];
  int bid = blockIdx.x;
  int n = bid >> 1, half = bid & 1;
  int t = threadIdx.x;
  s_wrt[t] = W_rt[t];
  s_wnm[t] = W_nm[t];
  if (t < 32) s_wnm[256 + t] = W_nm[256 + t];
  int rq[2], kk[2], i0[2], c0[2], l0[2], i1[2], c1[2], l1[2], qg[2];
  bool val[2];
  #pragma unroll
  for (int jj = 0; jj < 2; ++jj) {
    int j = t + jj*256;
    val[jj] = (j < 360);
    int js = val[jj] ? j : 0;
    rq[jj] = js / 45; kk[jj] = js % 45;
    qg[jj] = rq[jj]*90 + kk[jj] + half*45;
    int rem0 = 2*(kk[jj] + 45*half);
    i0[jj] = rem0 / 9;  c0[jj] = rem0 % 9;  l0[jj] = c_LOF[i0[jj]];
    int rem1 = rem0 + 1;
    i1[jj] = rem1 / 9;  c1[jj] = rem1 % 9;  l1[jj] = c_LOF[i1[jj]];
  }
  float accA[2][2] = {{0,0},{0,0}};
  float accB[2][2] = {{0,0},{0,0}};
  float2 mymem[2];
  #pragma unroll
  for (int jj = 0; jj < 2; ++jj)
    mymem[jj] = val[jj] ? __half22float2(A1h2[(size_t)n*NP2 + qg[jj]])
                        : make_float2(0.f, 0.f);
  int beg = offsets[n], end = offsets[n+1];
  const float4* f4 = (const float4*)facS;
  for (int base = beg; base < end; base += EC) {
    int m = min(EC, end - base);
    if (base != beg) __syncthreads();
    for (int idx = t; idx < m*(FW/4); idx += 256)
      ((float4*)s_e)[idx] = f4[(size_t)base*(FW/4) + idx];
    __syncthreads();
    int p = 0;
    for (; p + 3 < m; p += 4) {
      int sd0 = sndS[base+p+0], sd1 = sndS[base+p+1];
      int sd2 = sndS[base+p+2], sd3 = sndS[base+p+3];
      __half2 g0a = A1h2[(size_t)sd0*NP2 + qg[0]];
      __half2 g1a = A1h2[(size_t)sd1*NP2 + qg[0]];
      __half2 g2a = A1h2[(size_t)sd2*NP2 + qg[0]];
      __half2 g3a = A1h2[(size_t)sd3*NP2 + qg[0]];
      __half2 g0b, g1b, g2b, g3b;
      if (val[1]) {
        g0b = A1h2[(size_t)sd0*NP2 + qg[1]];
        g1b = A1h2[(size_t)sd1*NP2 + qg[1]];
        g2b = A1h2[(size_t)sd2*NP2 + qg[1]];
        g3b = A1h2[(size_t)sd3*NP2 + qg[1]];
      }
      #pragma unroll
      for (int x = 0; x < 4; ++x) {
        const float* e0 = s_e + (p+x)*FW;
        const float* x0 = e0 + 28;          // chi*enc (in-place from k_echi)
        __half2 ga = (x==0)?g0a:(x==1)?g1a:(x==2)?g2a:g3a;
        {
          float rv = e0[rq[0]];
          float2 gf = __half22float2(ga);
          accA[0][0] += gf.x * rv;
          accA[0][1] += gf.y * rv;
          accB[0][0] += rv * e0[8+i0[0]] * x0[c0[0]];
          accB[0][1] += rv * e0[8+i1[0]] * x0[c1[0]];
        }
        if (val[1]) {
          __half2 gb = (x==0)?g0b:(x==1)?g1b:(x==2)?g2b:g3b;
          float rv = e0[rq[1]];
          float2 gf = __half22float2(gb);
          accA[1][0] += gf.x * rv;
          accA[1][1] += gf.y * rv;
          accB[1][0] += rv * e0[8+i0[1]] * x0[c0[1]];
          accB[1][1] += rv * e0[8+i1[1]] * x0[c1[1]];
        }
      }
    }
    for (; p < m; ++p) {
      int sd = sndS[base+p];
      const float* e0 = s_e + p*FW;
      const float* x0 = e0 + 28;
      const __half2* Ah = A1h2 + (size_t)sd*NP2;
      #pragma unroll
      for (int jj = 0; jj < 2; ++jj) {
        if (val[jj]) {
          float rv = e0[rq[jj]];
          float2 gf = __half22float2(Ah[qg[jj]]);
          accA[jj][0] += gf.x * rv;
          accA[jj][1] += gf.y * rv;
          accB[jj][0] += rv * e0[8+i0[jj]] * x0[c0[jj]];
          accB[jj][1] += rv * e0[8+i1[jj]] * x0[c1[jj]];
        }
      }
    }
  }
  __syncthreads();
  float* s_a1 = s_e;   // reuse staging LDS as the A1 tile
  #pragma unroll
  for (int jj = 0; jj < 2; ++jj)
    if (val[jj]) {
      s_tile[rq[jj]*90 + 2*kk[jj]]     = accB[jj][0];
      s_tile[rq[jj]*90 + 2*kk[jj] + 1] = accB[jj][1];
      s_a1[rq[jj]*90 + 2*kk[jj]]       = mymem[jj].x;
      s_a1[rq[jj]*90 + 2*kk[jj] + 1]   = mymem[jj].y;
    }
  __syncthreads();
  float a2v[2][2];
  #pragma unroll
  for (int jj = 0; jj < 2; ++jj) {
    if (val[jj]) {
      float ab0 = 0.f, ab1 = 0.f;
      #pragma unroll
      for (int r = 0; r < NRB; ++r) {
        ab0 += s_tile[r*90 + 2*kk[jj]]     * s_wrt[l0[jj]*64 + r*8 + rq[jj]];
        ab1 += s_tile[r*90 + 2*kk[jj] + 1] * s_wrt[l1[jj]*64 + r*8 + rq[jj]];
      }
      float mem0 = mymem[jj].x * s_wnm[rq[jj]*36 + l0[jj]*9 + c0[jj]];
      float mem1 = mymem[jj].y * s_wnm[rq[jj]*36 + l1[jj]*9 + c1[jj]];
      a2v[jj][0] = (ab0 + accA[jj][0])*MPN + mem0;
      a2v[jj][1] = (ab1 + accA[jj][1])*MPN + mem1;
    }
  }
  __syncthreads();
  #pragma unroll
  for (int jj = 0; jj < 2; ++jj)
    if (val[jj]) {
      s_tile[rq[jj]*90 + 2*kk[jj]]     = a2v[jj][0];
      s_tile[rq[jj]*90 + 2*kk[jj] + 1] = a2v[jj][1];
    }
  __syncthreads();
  // epilogue: b0 from s_a1 (feats0), b1 from s_tile (feats1), paired float2 store
  float2* o2 = (float2*)out;
  if (half == 0) {
    for (int m2 = t; m2 < 288; m2 += 256) {
      int s = m2 / 36, rm = m2 % 36, l5 = rm / 9, c = rm % 9;
      float b0, b1;
      if (l5 == 0) {
        b0 = s_a1[s*90 + c];
        b1 = s_tile[s*90 + c];
      } else {
        b0 = 0.f; b1 = 0.f;
        for (int i = c_GB[l5]; i < c_GE[l5]; ++i) {
          float v0 = s_a1[s*90 + i*9 + c];
          float v1 = s_tile[s*90 + i*9 + c];
          b0 += c_PREF[i]*v0*v0;
          b1 += c_PREF[i]*v1*v1;
        }
      }
      o2[(size_t)((n*8 + s)*5 + l5)*9 + c] = make_float2(b0, b1);
    }
  } else {
    if (t < 72) {
      int s = t / 9, c = t % 9;
      float b0 = 0.f, b1 = 0.f;
      for (int i = 10; i < 20; ++i) {
        float v0 = s_a1[s*90 + (i-10)*9 + c];
        float v1 = s_tile[s*90 + (i-10)*9 + c];
        b0 += c_PREF[i]*v0*v0;
        b1 += c_PREF[i]*v1*v1;
      }
      o2[(size_t)((n*8 + s)*5 + 4)*9 + c] = make_float2(b0, b1);
    }
  }
}

extern "C" void kernel_launch(void* const* d_in, const int* in_sizes, int n_in,
                              void* d_out, int out_size, void* d_ws, size_t ws_size,
                              hipStream_t stream) {
  const float* pos    = (const float*)d_in[0];
  const float* shifts = (const float*)d_in[1];
  const float* W_emb  = (const float*)d_in[2];
  const float* W_rt   = (const float*)d_in[3];
  const float* W_nm   = (const float*)d_in[4];
  const int*   an     = (const int*)d_in[5];
  const int*   ei     = (const int*)d_in[6];
  float* out = (float*)d_out;

  char* ws = (char*)d_ws;
  size_t off = 0;
  auto carve = [&](size_t bytes) {
    void* p = ws + off;
    off = (off + bytes + 255) & ~(size_t)255;
    return p;
  };
  float*   facS    = (float*)carve((size_t)FW*NEDGE*sizeof(float));
  int*     sndS    = (int*)carve((size_t)NEDGE*sizeof(int));
  __half2* A1h2    = (__half2*)carve((size_t)NNODE*NEL*sizeof(__half));
  float*   chi     = (float*)carve((size_t)NNODE*NCH*sizeof(float));
  int*     counts  = (int*)carve((size_t)NNODE*sizeof(int));
  int*     offsets = (int*)carve((size_t)(NNODE+1)*sizeof(int));
  int*     cursor  = (int*)carve((size_t)NNODE*sizeof(int));

  size_t z0 = (size_t)((char*)chi - ws);
  size_t z1 = (size_t)((char*)counts - ws) + (size_t)NNODE*sizeof(int);
  hipMemsetAsync((char*)ws + z0, 0, z1 - z0, stream);
  k_count<<<(NEDGE+255)/256, 256, 0, stream>>>(ei, counts);
  k_scan<<<1, 1024, 0, stream>>>(counts, offsets, cursor);
  k_edgec<<<(NEDGE+255)/256, 256, 0, stream>>>(pos, shifts, ei, an, W_emb, cursor, facS, sndS);
  k_nodeA<<<NNODE*2, 256, 0, stream>>>(facS, offsets, W_rt, A1h2, chi);
  k_echi<<<(NEDGE+255)/256, 256, 0, stream>>>(facS, sndS, chi);
  k_nodeMP<<<NNODE*2, 256, 0, stream>>>(facS, offsets, sndS, W_rt, W_nm, A1h2, out);
}

// Round 14
// 112.537 us; speedup vs baseline: 1.4723x; 1.0222x over previous
//
#include <hip/hip_runtime.h>
#include <hip/hip_fp16.h>

#ifndef M_PIf
#define M_PIf 3.14159265358979323846f
#endif

constexpr int NNODE = 4000;
constexpr int NEDGE = 48000;
constexpr int NLA   = 20;
constexpr int NCH   = 9;
constexpr int NRB   = 8;
constexpr int NEL   = NRB * NLA * NCH;    // 1440
constexpr int NP2   = NEL / 2;            // 720 half2 pairs
constexpr int FW    = 40;                 // facS row width (floats)
constexpr int EC    = 32;                 // edge chunk per LDS stage
constexpr float CUT = 5.5f;
constexpr float MPN = 0.316227766016837933f;

__constant__ int   c_LOF[NLA]  = {0,1,1,1,2,2,2,2,2,2,3,3,3,3,3,3,3,3,3,3};
__constant__ float c_PREF[NLA] = {1,1,1,1,1,2,2,1,2,1,1,3,3,3,6,3,1,3,3,1};
__constant__ int   c_GB[4] = {0,0,1,4};
__constant__ int   c_GE[4] = {0,1,4,10};

__global__ void k_count(const int* __restrict__ ei, int* __restrict__ counts) {
  int e = blockIdx.x * blockDim.x + threadIdx.x;
  if (e >= NEDGE) return;
  atomicAdd(&counts[ei[NEDGE + e]], 1);
}

__global__ void k_scan(const int* __restrict__ counts, int* __restrict__ offsets,
                       int* __restrict__ cursor) {
  __shared__ int wsum[16];
  int t = threadIdx.x;
  int base = t*4;
  int c0 = (base+0 < NNODE) ? counts[base+0] : 0;
  int c1 = (base+1 < NNODE) ? counts[base+1] : 0;
  int c2 = (base+2 < NNODE) ? counts[base+2] : 0;
  int c3 = (base+3 < NNODE) ? counts[base+3] : 0;
  int s = c0+c1+c2+c3;
  int lane = t & 63, w = t >> 6;
  int incl = s;
  #pragma unroll
  for (int d = 1; d < 64; d <<= 1) {
    int v = __shfl_up(incl, d);
    if (lane >= d) incl += v;
  }
  if (lane == 63) wsum[w] = incl;
  __syncthreads();
  if (t < 16) {
    int v = wsum[t];
    int inc2 = v;
    #pragma unroll
    for (int d = 1; d < 16; d <<= 1) {
      int u = __shfl_up(inc2, d);
      if (t >= d) inc2 += u;
    }
    wsum[t] = inc2 - v;   // exclusive wave prefix
  }
  __syncthreads();
  int excl = wsum[w] + incl - s;
  int o0 = excl, o1 = o0+c0, o2 = o1+c1, o3 = o2+c2;
  if (base+0 < NNODE) { offsets[base+0]=o0; cursor[base+0]=o0; }
  if (base+1 < NNODE) { offsets[base+1]=o1; cursor[base+1]=o1; }
  if (base+2 < NNODE) { offsets[base+2]=o2; cursor[base+2]=o2; }
  if (base+3 < NNODE) { offsets[base+3]=o3; cursor[base+3]=o3; }
  if (t == 1023) offsets[NNODE] = excl + s;
}

__global__ void k_edgec(const float* __restrict__ pos, const float* __restrict__ shifts,
                        const int* __restrict__ ei, const int* __restrict__ an,
                        const float* __restrict__ W_emb,
                        int* __restrict__ cursor, float* __restrict__ facS,
                        int* __restrict__ sndS) {
  int e = blockIdx.x * blockDim.x + threadIdx.x;
  if (e >= NEDGE) return;
  int snd = ei[e];
  int rcv = ei[NEDGE + e];
  float vx = pos[rcv*3+0] - pos[snd*3+0] + shifts[e*3+0];
  float vy = pos[rcv*3+1] - pos[snd*3+1] + shifts[e*3+1];
  float vz = pos[rcv*3+2] - pos[snd*3+2] + shifts[e*3+2];
  float len = sqrtf(vx*vx + vy*vy + vz*vz);
  float inv = 1.0f / len;
  float x = vx*inv, y = vy*inv, z = vz*inv;
  float u  = len * (1.0f/CUT);
  float u2 = u*u;
  float u6 = u2*u2*u2;
  float fcut = 1.0f - 28.0f*u6 + 48.0f*u6*u - 21.0f*u6*u2;
  if (u >= 1.0f) fcut = 0.0f;
  float pre = sqrtf(2.0f/CUT) * fcut * inv;
  int p = atomicAdd(&cursor[rcv], 1);
  float* f = facS + (size_t)p*FW;
  // sin(n*pi*u) via Chebyshev recurrence: 1 sin + 1 cos + FMAs
  float s1 = __sinf(M_PIf * u);
  float cth = __cosf(M_PIf * u);
  float two_c = 2.0f * cth;
  float sm1 = 0.0f, sc = s1;
  #pragma unroll
  for (int j = 0; j < NRB; ++j) {
    f[j] = pre * sc;
    float nx = two_c * sc - sm1;
    sm1 = sc; sc = nx;
  }
  float ang[NLA];
  ang[0]=1.0f; ang[1]=x; ang[2]=y; ang[3]=z;
  ang[4]=x*x; ang[5]=x*y; ang[6]=x*z; ang[7]=y*y; ang[8]=y*z; ang[9]=z*z;
  ang[10]=ang[4]*x; ang[11]=ang[4]*y; ang[12]=ang[4]*z;
  ang[13]=x*ang[7]; ang[14]=ang[5]*z; ang[15]=x*ang[9];
  ang[16]=ang[7]*y; ang[17]=ang[7]*z; ang[18]=y*ang[9]; ang[19]=ang[9]*z;
  #pragma unroll
  for (int i = 0; i < NLA; ++i) f[8+i] = ang[i];
  int as_ = an[snd], ar_ = an[rcv];
  int sps = (as_==1)?0:(as_==6)?1:(as_==7)?2:3;
  int spr = (ar_==1)?0:(ar_==6)?1:(ar_==7)?2:3;
  float es0=W_emb[sps*3+0], es1=W_emb[sps*3+1], es2=W_emb[sps*3+2];
  float er0=W_emb[spr*3+0], er1=W_emb[spr*3+1], er2=W_emb[spr*3+2];
  f[28]=es0*er0; f[29]=es0*er1; f[30]=es0*er2;
  f[31]=es1*er0; f[32]=es1*er1; f[33]=es1*er2;
  f[34]=es2*er0; f[35]=es2*er1; f[36]=es2*er2;
  f[37]=0.f; f[38]=0.f; f[39]=0.f;
  sndS[p] = snd;
}

// In-place: facS[p][28..36] = chi[snd_p] * enc_p  (k_nodeA consumed enc already)
__global__ void k_echi(float* __restrict__ facS, const int* __restrict__ sndS,
                       const float* __restrict__ chi) {
  int p = blockIdx.x * blockDim.x + threadIdx.x;
  if (p >= NEDGE) return;
  int snd = sndS[p];
  float* f = facS + (size_t)p*FW;
  #pragma unroll
  for (int c = 0; c < 9; ++c)
    f[28 + c] = chi[snd*9 + c] * f[28 + c];
}

// ---- split-node kernels: block = (node,half);
// pair slot j in [0,360): r = j/45, kk = j%45.
// A1h2 layout (contiguous per half): q = half*360 + j  -> block gathers are
// fully coalesced (thread t reads row[half*360 + t], row[half*360 + 256 + t]).
// j0 = t (valid always), j1 = t+256 (valid t<104)

__global__ __launch_bounds__(256, 8) void k_nodeA(
    const float* __restrict__ facS, const int* __restrict__ offsets,
    const float* __restrict__ W_rt,
    __half2* __restrict__ A1h2,
    float* __restrict__ chi) {
  __shared__ float s_wrt[256];
  __shared__ float s_e[EC*FW];
  __shared__ float s_tile[8*90];
  __shared__ float s_B[288];
  int bid = blockIdx.x;
  int n = bid >> 1, half = bid & 1;
  int t = threadIdx.x;
  s_wrt[t] = W_rt[t];
  int rq[2], kk[2], i0[2], c0[2], l0[2], i1[2], c1[2], l1[2], qg[2];
  bool val[2];
  #pragma unroll
  for (int jj = 0; jj < 2; ++jj) {
    int j = t + jj*256;
    val[jj] = (j < 360);
    int js = val[jj] ? j : 0;
    rq[jj] = js / 45; kk[jj] = js % 45;
    qg[jj] = half*360 + js;            // contiguous-per-half layout
    int rem0 = 2*(kk[jj] + 45*half);
    i0[jj] = rem0 / 9;  c0[jj] = rem0 % 9;  l0[jj] = c_LOF[i0[jj]];
    int rem1 = rem0 + 1;
    i1[jj] = rem1 / 9;  c1[jj] = rem1 % 9;  l1[jj] = c_LOF[i1[jj]];
  }
  float acc[2][2] = {{0,0},{0,0}};
  int beg = offsets[n], end = offsets[n+1];
  const float4* f4 = (const float4*)facS;
  for (int base = beg; base < end; base += EC) {
    int m = min(EC, end - base);
    if (base != beg) __syncthreads();
    for (int idx = t; idx < m*(FW/4); idx += 256)
      ((float4*)s_e)[idx] = f4[(size_t)base*(FW/4) + idx];
    __syncthreads();
    for (int p = 0; p < m; ++p) {
      const float* e0 = s_e + p*FW;
      #pragma unroll
      for (int jj = 0; jj < 2; ++jj) {
        if (val[jj]) {
          float rv = e0[rq[jj]];
          acc[jj][0] += rv * e0[8+i0[jj]] * e0[28+c0[jj]];
          acc[jj][1] += rv * e0[8+i1[jj]] * e0[28+c1[jj]];
        }
      }
    }
  }
  __syncthreads();
  #pragma unroll
  for (int jj = 0; jj < 2; ++jj)
    if (val[jj]) {
      s_tile[rq[jj]*90 + 2*kk[jj]]     = acc[jj][0];
      s_tile[rq[jj]*90 + 2*kk[jj] + 1] = acc[jj][1];
    }
  __syncthreads();
  float a1v[2][2];
  #pragma unroll
  for (int jj = 0; jj < 2; ++jj) {
    if (val[jj]) {
      float ab0 = 0.f, ab1 = 0.f;
      #pragma unroll
      for (int r = 0; r < NRB; ++r) {
        ab0 += s_tile[r*90 + 2*kk[jj]]     * s_wrt[l0[jj]*64 + r*8 + rq[jj]];
        ab1 += s_tile[r*90 + 2*kk[jj] + 1] * s_wrt[l1[jj]*64 + r*8 + rq[jj]];
      }
      a1v[jj][0] = ab0; a1v[jj][1] = ab1;
      A1h2[(size_t)n*NP2 + qg[jj]] = __floats2half2_rn(ab0, ab1);
    }
  }
  __syncthreads();
  #pragma unroll
  for (int jj = 0; jj < 2; ++jj)
    if (val[jj]) {
      s_tile[rq[jj]*90 + 2*kk[jj]]     = a1v[jj][0];
      s_tile[rq[jj]*90 + 2*kk[jj] + 1] = a1v[jj][1];
    }
  __syncthreads();
  // chi only (feats written by k_nodeMP as float2)
  if (half == 0) {
    for (int m2 = t; m2 < 288; m2 += 256) {
      int s = m2 / 36, rm = m2 % 36, l5 = rm / 9, c = rm % 9;
      float b;
      if (l5 == 0) b = s_tile[s*90 + c];
      else {
        b = 0.f;
        for (int i = c_GB[l5]; i < c_GE[l5]; ++i) {
          float v = s_tile[s*90 + i*9 + c];
          b += c_PREF[i]*v*v;
        }
      }
      s_B[m2] = b;
    }
    __syncthreads();
    if (t < 9) {
      float x = 0.f;
      #pragma unroll
      for (int u = 0; u < 32; ++u) x += s_B[u*9 + t];
      atomicAdd(&chi[n*9 + t], x);
    }
  } else {
    if (t < 72) {
      int s = t / 9, c = t % 9;
      float b = 0.f;
      for (int i = 10; i < 20; ++i) {
        float v = s_tile[s*90 + (i-10)*9 + c];
        b += c_PREF[i]*v*v;
      }
      s_B[t] = b;
    }
    __syncthreads();
    if (t < 9) {
      float x = 0.f;
      #pragma unroll
      for (int u = 0; u < 8; ++u) x += s_B[u*9 + t];
      atomicAdd(&chi[n*9 + t], x);
    }
  }
}

__global__ __launch_bounds__(256, 8) void k_nodeMP(
    const float* __restrict__ facS, const int* __restrict__ offsets,
    const int* __restrict__ sndS,
    const float* __restrict__ W_rt, const float* __restrict__ W_nm,
    const __half2* __restrict__ A1h2,
    float* __restrict__ out) {
  __shared__ float s_wrt[256];
  __shared__ float s_wnm[288];
  __shared__ float s_e[EC*FW];     // reused as a1 tile (720 floats) in epilogue
  __shared__ float s_tile[8*90];
  int bid = blockIdx.x;
  int n = bid >> 1, half = bid & 1;
  int t = threadIdx.x;
  s_wrt[t] = W_rt[t];
  s_wnm[t] = W_nm[t];
  if (t < 32) s_wnm[256 + t] = W_nm[256 + t];
  int rq[2], kk[2], i0[2], c0[2], l0[2], i1[2], c1[2], l1[2], qg[2];
  bool val[2];
  #pragma unroll
  for (int jj = 0; jj < 2; ++jj) {
    int j = t + jj*256;
    val[jj] = (j < 360);
    int js = val[jj] ? j : 0;
    rq[jj] = js / 45; kk[jj] = js % 45;
    qg[jj] = half*360 + js;            // contiguous-per-half layout
    int rem0 = 2*(kk[jj] + 45*half);
    i0[jj] = rem0 / 9;  c0[jj] = rem0 % 9;  l0[jj] = c_LOF[i0[jj]];
    int rem1 = rem0 + 1;
    i1[jj] = rem1 / 9;  c1[jj] = rem1 % 9;  l1[jj] = c_LOF[i1[jj]];
  }
  float accA[2][2] = {{0,0},{0,0}};
  float accB[2][2] = {{0,0},{0,0}};
  float2 mymem[2];
  #pragma unroll
  for (int jj = 0; jj < 2; ++jj)
    mymem[jj] = val[jj] ? __half22float2(A1h2[(size_t)n*NP2 + qg[jj]])
                        : make_float2(0.f, 0.f);
  int beg = offsets[n], end = offsets[n+1];
  const float4* f4 = (const float4*)facS;
  for (int base = beg; base < end; base += EC) {
    int m = min(EC, end - base);
    if (base != beg) __syncthreads();
    for (int idx = t; idx < m*(FW/4); idx += 256)
      ((float4*)s_e)[idx] = f4[(size_t)base*(FW/4) + idx];
    __syncthreads();
    int p = 0;
    for (; p + 3 < m; p += 4) {
      int sd0 = sndS[base+p+0], sd1 = sndS[base+p+1];
      int sd2 = sndS[base+p+2], sd3 = sndS[base+p+3];
      __half2 g0a = A1h2[(size_t)sd0*NP2 + qg[0]];
      __half2 g1a = A1h2[(size_t)sd1*NP2 + qg[0]];
      __half2 g2a = A1h2[(size_t)sd2*NP2 + qg[0]];
      __half2 g3a = A1h2[(size_t)sd3*NP2 + qg[0]];
      __half2 g0b, g1b, g2b, g3b;
      if (val[1]) {
        g0b = A1h2[(size_t)sd0*NP2 + qg[1]];
        g1b = A1h2[(size_t)sd1*NP2 + qg[1]];
        g2b = A1h2[(size_t)sd2*NP2 + qg[1]];
        g3b = A1h2[(size_t)sd3*NP2 + qg[1]];
      }
      #pragma unroll
      for (int x = 0; x < 4; ++x) {
        const float* e0 = s_e + (p+x)*FW;
        const float* x0 = e0 + 28;          // chi*enc (in-place from k_echi)
        __half2 ga = (x==0)?g0a:(x==1)?g1a:(x==2)?g2a:g3a;
        {
          float rv = e0[rq[0]];
          float2 gf = __half22float2(ga);
          accA[0][0] += gf.x * rv;
          accA[0][1] += gf.y * rv;
          accB[0][0] += rv * e0[8+i0[0]] * x0[c0[0]];
          accB[0][1] += rv * e0[8+i1[0]] * x0[c1[0]];
        }
        if (val[1]) {
          __half2 gb = (x==0)?g0b:(x==1)?g1b:(x==2)?g2b:g3b;
          float rv = e0[rq[1]];
          float2 gf = __half22float2(gb);
          accA[1][0] += gf.x * rv;
          accA[1][1] += gf.y * rv;
          accB[1][0] += rv * e0[8+i0[1]] * x0[c0[1]];
          accB[1][1] += rv * e0[8+i1[1]] * x0[c1[1]];
        }
      }
    }
    for (; p < m; ++p) {
      int sd = sndS[base+p];
      const float* e0 = s_e + p*FW;
      const float* x0 = e0 + 28;
      const __half2* Ah = A1h2 + (size_t)sd*NP2;
      #pragma unroll
      for (int jj = 0; jj < 2; ++jj) {
        if (val[jj]) {
          float rv = e0[rq[jj]];
          float2 gf = __half22float2(Ah[qg[jj]]);
          accA[jj][0] += gf.x * rv;
          accA[jj][1] += gf.y * rv;
          accB[jj][0] += rv * e0[8+i0[jj]] * x0[c0[jj]];
          accB[jj][1] += rv * e0[8+i1[jj]] * x0[c1[jj]];
        }
      }
    }
  }
  __syncthreads();
  float* s_a1 = s_e;   // reuse staging LDS as the A1 tile
  #pragma unroll
  for (int jj = 0; jj < 2; ++jj)
    if (val[jj]) {
      s_tile[rq[jj]*90 + 2*kk[jj]]     = accB[jj][0];
      s_tile[rq[jj]*90 + 2*kk[jj] + 1] = accB[jj][1];
      s_a1[rq[jj]*90 + 2*kk[jj]]       = mymem[jj].x;
      s_a1[rq[jj]*90 + 2*kk[jj] + 1]   = mymem[jj].y;
    }
  __syncthreads();
  float a2v[2][2];
  #pragma unroll
  for (int jj = 0; jj < 2; ++jj) {
    if (val[jj]) {
      float ab0 = 0.f, ab1 = 0.f;
      #pragma unroll
      for (int r = 0; r < NRB; ++r) {
        ab0 += s_tile[r*90 + 2*kk[jj]]     * s_wrt[l0[jj]*64 + r*8 + rq[jj]];
        ab1 += s_tile[r*90 + 2*kk[jj] + 1] * s_wrt[l1[jj]*64 + r*8 + rq[jj]];
      }
      float mem0 = mymem[jj].x * s_wnm[rq[jj]*36 + l0[jj]*9 + c0[jj]];
      float mem1 = mymem[jj].y * s_wnm[rq[jj]*36 + l1[jj]*9 + c1[jj]];
      a2v[jj][0] = (ab0 + accA[jj][0])*MPN + mem0;
      a2v[jj][1] = (ab1 + accA[jj][1])*MPN + mem1;
    }
  }
  __syncthreads();
  #pragma unroll
  for (int jj = 0; jj < 2; ++jj)
    if (val[jj]) {
      s_tile[rq[jj]*90 + 2*kk[jj]]     = a2v[jj][0];
      s_tile[rq[jj]*90 + 2*kk[jj] + 1] = a2v[jj][1];
    }
  __syncthreads();
  // epilogue: b0 from s_a1 (feats0), b1 from s_tile (feats1), paired float2 store
  float2* o2 = (float2*)out;
  if (half == 0) {
    for (int m2 = t; m2 < 288; m2 += 256) {
      int s = m2 / 36, rm = m2 % 36, l5 = rm / 9, c = rm % 9;
      float b0, b1;
      if (l5 == 0) {
        b0 = s_a1[s*90 + c];
        b1 = s_tile[s*90 + c];
      } else {
        b0 = 0.f; b1 = 0.f;
        for (int i = c_GB[l5]; i < c_GE[l5]; ++i) {
          float v0 = s_a1[s*90 + i*9 + c];
          float v1 = s_tile[s*90 + i*9 + c];
          b0 += c_PREF[i]*v0*v0;
          b1 += c_PREF[i]*v1*v1;
        }
      }
      o2[(size_t)((n*8 + s)*5 + l5)*9 + c] = make_float2(b0, b1);
    }
  } else {
    if (t < 72) {
      int s = t / 9, c = t % 9;
      float b0 = 0.f, b1 = 0.f;
      for (int i = 10; i < 20; ++i) {
        float v0 = s_a1[s*90 + (i-10)*9 + c];
        float v1 = s_tile[s*90 + (i-10)*9 + c];
        b0 += c_PREF[i]*v0*v0;
        b1 += c_PREF[i]*v1*v1;
      }
      o2[(size_t)((n*8 + s)*5 + 4)*9 + c] = make_float2(b0, b1);
    }
  }
}

extern "C" void kernel_launch(void* const* d_in, const int* in_sizes, int n_in,
                              void* d_out, int out_size, void* d_ws, size_t ws_size,
                              hipStream_t stream) {
  const float* pos    = (const float*)d_in[0];
  const float* shifts = (const float*)d_in[1];
  const float* W_emb  = (const float*)d_in[2];
  const float* W_rt   = (const float*)d_in[3];
  const float* W_nm   = (const float*)d_in[4];
  const int*   an     = (const int*)d_in[5];
  const int*   ei     = (const int*)d_in[6];
  float* out = (float*)d_out;

  char* ws = (char*)d_ws;
  size_t off = 0;
  auto carve = [&](size_t bytes) {
    void* p = ws + off;
    off = (off + bytes + 255) & ~(size_t)255;
    return p;
  };
  float*   facS    = (float*)carve((size_t)FW*NEDGE*sizeof(float));
  int*     sndS    = (int*)carve((size_t)NEDGE*sizeof(int));
  __half2* A1h2    = (__half2*)carve((size_t)NNODE*NEL*sizeof(__half));
  float*   chi     = (float*)carve((size_t)NNODE*NCH*sizeof(float));
  int*     counts  = (int*)carve((size_t)NNODE*sizeof(int));
  int*     offsets = (int*)carve((size_t)(NNODE+1)*sizeof(int));
  int*     cursor  = (int*)carve((size_t)NNODE*sizeof(int));

  size_t z0 = (size_t)((char*)chi - ws);
  size_t z1 = (size_t)((char*)counts - ws) + (size_t)NNODE*sizeof(int);
  hipMemsetAsync((char*)ws + z0, 0, z1 - z0, stream);
  k_count<<<(NEDGE+255)/256, 256, 0, stream>>>(ei, counts);
  k_scan<<<1, 1024, 0, stream>>>(counts, offsets, cursor);
  k_edgec<<<(NEDGE+255)/256, 256, 0, stream>>>(pos, shifts, ei, an, W_emb, cursor, facS, sndS);
  k_nodeA<<<NNODE*2, 256, 0, stream>>>(facS, offsets, W_rt, A1h2, chi);
  k_echi<<<(NEDGE+255)/256, 256, 0, stream>>>(facS, sndS, chi);
  k_nodeMP<<<NNODE*2, 256, 0, stream>>>(facS, offsets, sndS, W_rt, W_nm, A1h2, out);
}